// Round 10
// baseline (572.056 us; speedup 1.0000x reference)
//
#include <hip/hip_runtime.h>
#include <stdint.h>
#include <math.h>

#define Bk 2
#define Nk 2048
#define Ek 1024
#define Hk 16
#define DHk 64
#define BLENDW 5e-5    // blend ramp width on scaled-score gap
#define PRECAND 96     // prefilter count target (>=65 + margin)
#define CANDCAP 128

using short8 = __attribute__((ext_vector_type(8))) short;
using f32x4  = __attribute__((ext_vector_type(4))) float;

__device__ __forceinline__ unsigned short bf16rne(float f) {
    const unsigned u = __float_as_uint(f);
    return (unsigned short)((u + 0x7FFFu + ((u >> 16) & 1u)) >> 16);
}

// ---------------------------------------------------------------------------
// f32 -> (hi bf16, lo bf16) split: x ~= hi + lo, rel err ~2^-17.
// v13: two segments (X and W) in ONE launch - halves cvt launch count.
// ---------------------------------------------------------------------------
__global__ __launch_bounds__(256) void cvt_split2(
    const float* __restrict__ inA, unsigned short* __restrict__ ohA,
    unsigned short* __restrict__ olA, int nA,
    const float* __restrict__ inB, unsigned short* __restrict__ ohB,
    unsigned short* __restrict__ olB)
{
    const int b = blockIdx.x;
    const float* in; unsigned short* oh; unsigned short* ol; int i;
    if (b < nA) { in = inA; oh = ohA; ol = olA; i = b * 256 + threadIdx.x; }
    else        { in = inB; oh = ohB; ol = olB; i = (b - nA) * 256 + threadIdx.x; }

    const float4 a = ((const float4*)in)[i * 2];
    const float4 c = ((const float4*)in)[i * 2 + 1];
    float x[8] = {a.x, a.y, a.z, a.w, c.x, c.y, c.z, c.w};
    unsigned short hs[8], ls[8];
#pragma unroll
    for (int j = 0; j < 8; ++j) {
        hs[j] = bf16rne(x[j]);
        const float hf = __uint_as_float((unsigned)hs[j] << 16);
        ls[j] = bf16rne(x[j] - hf);
    }
    uint4 ho, lo;
    ho.x = hs[0] | ((unsigned)hs[1] << 16); ho.y = hs[2] | ((unsigned)hs[3] << 16);
    ho.z = hs[4] | ((unsigned)hs[5] << 16); ho.w = hs[6] | ((unsigned)hs[7] << 16);
    lo.x = ls[0] | ((unsigned)ls[1] << 16); lo.y = ls[2] | ((unsigned)ls[3] << 16);
    lo.z = ls[4] | ((unsigned)ls[5] << 16); lo.w = ls[6] | ((unsigned)ls[7] << 16);
    ((uint4*)oh)[i] = ho;
    ((uint4*)ol)[i] = lo;
}

// ---------------------------------------------------------------------------
// Split-bf16 MFMA GEMM: C[m,c] = sum_k X[m,k]W[c,k] + bias[c]
//   = Xh*Wh + Xh*Wl + Xl*Wh  (3 MFMA per k-tile; rel err ~2^-17 < f32 GEMM)
// v13: tile 64x64 (was 128x64). Grid (16,64)=1024 blocks = 4 blocks/CU (was
// 512 = 2/CU): the 2-barrier K-loop was latency-bound at ~6% MFMA-pipe util
// with only 2 blocks/CU to overlap; 4/CU gives cross-block overlap (m114).
// LDS 20KB/block (4x fits in 80KB). Per-thread loads stay 16B uniform.
// MODE 0: out[m*Ek+c]; MODE 1: split-head f32 out; obf != null -> bf16 copy in
// FRAGMENT-CONTIGUOUS layout (verified r8): short_off = (nn>>4)*1024 +
// (dd>>5)*512 + ((((dd>>3)&3)*16 + (nn&15))*8) + (dd&7).
// ---------------------------------------------------------------------------
template<int MODE>
__global__ __launch_bounds__(256, 4) void gemm_mfma(
    const unsigned short* __restrict__ Xh, const unsigned short* __restrict__ Xl,
    const unsigned short* __restrict__ Wh, const unsigned short* __restrict__ Wl,
    const float* __restrict__ bias, float* __restrict__ out,
    unsigned short* __restrict__ obf)
{
    __shared__ unsigned short Ah[64][40], Al[64][40];   // [m][k] pad->80B rows
    __shared__ unsigned short Bh[64][40], Bl[64][40];   // [c][k]

    const int tid  = threadIdx.x;
    const int lane = tid & 63;
    const int wv   = tid >> 6;            // 0..3; wave owns rows wv*16..+15
    const int n16  = lane & 15;
    const int quad = lane >> 4;
    const int mBase = blockIdx.y * 64;
    const int nBase = blockIdx.x * 64;

    f32x4 acc[4];
#pragma unroll
    for (int j = 0; j < 4; ++j) acc[j] = (f32x4){0.f, 0.f, 0.f, 0.f};

    const int row = tid >> 2, off = (tid & 3) * 8;     // 8 shorts (16B)/thread
    const size_t aIdx = (size_t)(mBase + row) * Ek + off;
    const size_t bIdx = (size_t)(nBase + row) * Ek + off;

    for (int kt = 0; kt < Ek; kt += 32) {
        const uint4 ah0 = *(const uint4*)(Xh + aIdx + kt);
        const uint4 al0 = *(const uint4*)(Xl + aIdx + kt);
        const uint4 bh0 = *(const uint4*)(Wh + bIdx + kt);
        const uint4 bl0 = *(const uint4*)(Wl + bIdx + kt);
        __syncthreads();
        *(uint4*)&Ah[row][off] = ah0;
        *(uint4*)&Al[row][off] = al0;
        *(uint4*)&Bh[row][off] = bh0;
        *(uint4*)&Bl[row][off] = bl0;
        __syncthreads();

        const short8 fa_h = *(const short8*)&Ah[wv*16 + n16][quad*8];
        const short8 fa_l = *(const short8*)&Al[wv*16 + n16][quad*8];
#pragma unroll
        for (int ct = 0; ct < 4; ++ct) {
            const short8 fb_h = *(const short8*)&Bh[ct*16 + n16][quad*8];
            const short8 fb_l = *(const short8*)&Bl[ct*16 + n16][quad*8];
            acc[ct] = __builtin_amdgcn_mfma_f32_16x16x32_bf16(fa_h, fb_h, acc[ct], 0, 0, 0);
            acc[ct] = __builtin_amdgcn_mfma_f32_16x16x32_bf16(fa_h, fb_l, acc[ct], 0, 0, 0);
            acc[ct] = __builtin_amdgcn_mfma_f32_16x16x32_bf16(fa_l, fb_h, acc[ct], 0, 0, 0);
        }
    }

    // epilogue: D row = quad*4+reg (within 16-tile), col = n16
#pragma unroll
    for (int ct = 0; ct < 4; ++ct) {
        const int c  = nBase + ct*16 + n16;
        const float bv = bias[c];
#pragma unroll
        for (int reg = 0; reg < 4; ++reg) {
            const int m = mBase + wv*16 + quad*4 + reg;
            const float o = acc[ct][reg] + bv;
            if (MODE == 0) {
                out[(size_t)m * Ek + c] = o;
            } else {
                const int bb2 = m >> 11, nn = m & 2047;
                const int hh2 = c >> 6,  dd = c & 63;
                const size_t sb = (size_t)(bb2*Hk + hh2) * Nk * DHk;
                out[sb + (size_t)nn * DHk + dd] = o;
                if (obf) {
                    const size_t kdst = sb + (size_t)(nn >> 4) * 1024
                                      + ((dd >> 5) * 512)
                                      + ((((dd >> 3) & 3) * 16 + (nn & 15)) * 8)
                                      + (dd & 7);
                    obf[kdst] = bf16rne(o);
                }
            }
        }
    }
}

// ---------------------------------------------------------------------------
__device__ __forceinline__ unsigned fkey(float s) {
    const unsigned b = __float_as_uint(s);
    return (b & 0x80000000u) ? ~b : (b | 0x80000000u);
}
__device__ __forceinline__ unsigned long long dkey(double s) {
    unsigned long long b = (unsigned long long)__double_as_longlong(s);
    return (b & 0x8000000000000000ull) ? ~b : (b | 0x8000000000000000ull);
}
__device__ __forceinline__ double dinv(unsigned long long u) {
    const unsigned long long b =
        (u & 0x8000000000000000ull) ? (u & 0x7fffffffffffffffull) : ~u;
    return __longlong_as_double((long long)b);
}

// ---------------------------------------------------------------------------
// DPP wave-64 reductions / scan (rocPRIM & LLVM AtomicOptimizer patterns).
// ---------------------------------------------------------------------------
__device__ __forceinline__ int dpp_wsum_i32(int x) {
#define STEP(C) x += __builtin_amdgcn_update_dpp(0, x, C, 0xf, 0xf, true);
    STEP(0x111) STEP(0x112) STEP(0x114) STEP(0x118) STEP(0x142) STEP(0x143)
#undef STEP
    return __builtin_amdgcn_readlane(x, 63);
}
__device__ __forceinline__ float dpp_wsum_f32(float x) {
#define STEP(C) { const int t_ = __builtin_amdgcn_update_dpp(0, __float_as_int(x), C, 0xf, 0xf, true); \
                  x += __int_as_float(t_); }
    STEP(0x111) STEP(0x112) STEP(0x114) STEP(0x118) STEP(0x142) STEP(0x143)
#undef STEP
    return __int_as_float(__builtin_amdgcn_readlane(__float_as_int(x), 63));
}
__device__ __forceinline__ float dpp_wmax_f32(float x) {
#define STEP(C) { const int t_ = __builtin_amdgcn_update_dpp(__float_as_int(x), __float_as_int(x), C, 0xf, 0xf, false); \
                  x = fmaxf(x, __int_as_float(t_)); }
    STEP(0x111) STEP(0x112) STEP(0x114) STEP(0x118) STEP(0x142) STEP(0x143)
#undef STEP
    return __int_as_float(__builtin_amdgcn_readlane(__float_as_int(x), 63));
}
__device__ __forceinline__ unsigned dpp_wmin_u32(unsigned x) {
#define STEP(C) { const unsigned t_ = (unsigned)__builtin_amdgcn_update_dpp((int)x, (int)x, C, 0xf, 0xf, false); \
                  x = x < t_ ? x : t_; }
    STEP(0x111) STEP(0x112) STEP(0x114) STEP(0x118) STEP(0x142) STEP(0x143)
#undef STEP
    return (unsigned)__builtin_amdgcn_readlane((int)x, 63);
}
__device__ __forceinline__ unsigned dpp_wmax_u32(unsigned x) {
#define STEP(C) { const unsigned t_ = (unsigned)__builtin_amdgcn_update_dpp((int)x, (int)x, C, 0xf, 0xf, false); \
                  x = x > t_ ? x : t_; }
    STEP(0x111) STEP(0x112) STEP(0x114) STEP(0x118) STEP(0x142) STEP(0x143)
#undef STEP
    return (unsigned)__builtin_amdgcn_readlane((int)x, 63);
}
// inclusive prefix-sum across 64 lanes (LLVM buildScan pattern)
__device__ __forceinline__ int dpp_wprefix_incl_i32(int x) {
    x += __builtin_amdgcn_update_dpp(0, x, 0x111, 0xf, 0xf, true);  // row_shr:1
    x += __builtin_amdgcn_update_dpp(0, x, 0x112, 0xf, 0xf, true);  // row_shr:2
    x += __builtin_amdgcn_update_dpp(0, x, 0x114, 0xf, 0xf, true);  // row_shr:4
    x += __builtin_amdgcn_update_dpp(0, x, 0x118, 0xf, 0xf, true);  // row_shr:8
    x += __builtin_amdgcn_update_dpp(0, x, 0x142, 0xa, 0xf, true);  // bcast15 -> rows 1,3
    x += __builtin_amdgcn_update_dpp(0, x, 0x143, 0xc, 0xf, true);  // bcast31 -> rows 2,3
    return x;
}

// ---------------------------------------------------------------------------
// Per-row top-k: prefilter -> f64 recheck -> exact top-64 + rank-65 blend.
// (unchanged from v12 - proven 297 us)
// ---------------------------------------------------------------------------
__device__ __forceinline__ void proc_row(
    const int lane, const int lrow,
    unsigned s0, unsigned s1, unsigned s2, unsigned s3,
    unsigned s4, unsigned s5, unsigned s6, unsigned s7,
    unsigned s8, unsigned s9, unsigned s10, unsigned s11,
    unsigned s12, unsigned s13, unsigned s14, unsigned s15,
    const float* __restrict__ Kb, const float (*qsf)[68],
    unsigned long long (*ck)[CANDCAP], unsigned (*ci)[CANDCAP],
    unsigned long long (*wvi)[64], unsigned (*eq_idx)[64],
    int& i65_out, float& lam_out)
{
    const unsigned long long lmask = (1ull << lane) - 1ull;

    // shifted copies: q_w = lo-half in compare space (hi-half compares use s_w)
    const unsigned q0 = s0 << 16,  q1 = s1 << 16,  q2 = s2 << 16,  q3 = s3 << 16;
    const unsigned q4 = s4 << 16,  q5 = s5 << 16,  q6 = s6 << 16,  q7 = s7 << 16;
    const unsigned q8 = s8 << 16,  q9 = s9 << 16,  q10 = s10 << 16, q11 = s11 << 16;
    const unsigned q12 = s12 << 16, q13 = s13 << 16, q14 = s14 << 16, q15 = s15 << 16;

    // A) bracket: per-lane top-2 over the 32 junk-space values.
    unsigned m1 = 0u, m2 = 0u;
#define T2(V) { const unsigned t_ = (V) < m1 ? (V) : m1; \
                m1 = m1 > (V) ? m1 : (V);  m2 = m2 > t_ ? m2 : t_; }
    T2(s0)  T2(s1)  T2(s2)  T2(s3)  T2(s4)  T2(s5)  T2(s6)  T2(s7)
    T2(s8)  T2(s9)  T2(s10) T2(s11) T2(s12) T2(s13) T2(s14) T2(s15)
    T2(q0)  T2(q1)  T2(q2)  T2(q3)  T2(q4)  T2(q5)  T2(q6)  T2(q7)
    T2(q8)  T2(q9)  T2(q10) T2(q11) T2(q12) T2(q13) T2(q14) T2(q15)
#undef T2
    unsigned lo16 = dpp_wmin_u32(m2) >> 16;   // count(>=lo16) >= 2/lane -> >=128
    unsigned hi16 = dpp_wmax_u32(m1) >> 16;   // count(>=hi16+1) == 0

    // binary search: largest TH with count >= PRECAND; window-accept [96,128]
    while (lo16 < hi16) {
        const unsigned mid = lo16 + ((hi16 - lo16) >> 1) + 1u;
        const unsigned M = mid << 16;
        int c0 = 0, c1 = 0, c2 = 0, c3 = 0;    // 4 accums: break dep chain
        c0 += (s0  >= M); c0 += (q0  >= M); c0 += (s1  >= M); c0 += (q1  >= M);
        c0 += (s2  >= M); c0 += (q2  >= M); c0 += (s3  >= M); c0 += (q3  >= M);
        c1 += (s4  >= M); c1 += (q4  >= M); c1 += (s5  >= M); c1 += (q5  >= M);
        c1 += (s6  >= M); c1 += (q6  >= M); c1 += (s7  >= M); c1 += (q7  >= M);
        c2 += (s8  >= M); c2 += (q8  >= M); c2 += (s9  >= M); c2 += (q9  >= M);
        c2 += (s10 >= M); c2 += (q10 >= M); c2 += (s11 >= M); c2 += (q11 >= M);
        c3 += (s12 >= M); c3 += (q12 >= M); c3 += (s13 >= M); c3 += (q13 >= M);
        c3 += (s14 >= M); c3 += (q14 >= M); c3 += (s15 >= M); c3 += (q15 >= M);
        const int c = dpp_wsum_i32((c0 + c1) + (c2 + c3));
        if (c >= PRECAND) {
            lo16 = mid;
            if (c <= CANDCAP) break;       // window accept (superset-safe)
        } else hi16 = mid - 1u;
    }
    const unsigned THsh = lo16 << 16;

    // collect candidates, LANE-MAJOR: per-lane count -> DPP prefix -> scatter
    int cnt = 0;
#define CC(S, Q) { cnt += ((Q) >= THsh); cnt += ((S) >= THsh); }
    CC(s0, q0)    CC(s1, q1)    CC(s2, q2)    CC(s3, q3)
    CC(s4, q4)    CC(s5, q5)    CC(s6, q6)    CC(s7, q7)
    CC(s8, q8)    CC(s9, q9)    CC(s10, q10)  CC(s11, q11)
    CC(s12, q12)  CC(s13, q13)  CC(s14, q14)  CC(s15, q15)
#undef CC
    const int incl = dpp_wprefix_incl_i32(cnt);
    int pos = incl - cnt;                       // exclusive prefix
    int nc = __builtin_amdgcn_readlane(incl, 63);
    if (nc > CANDCAP) nc = CANDCAP;
#define CE(W, S, Q) { \
        if ((Q) >= THsh) { \
            if (pos < CANDCAP) \
                ci[lrow][pos] = (unsigned)((((W) >> 2) * 512) + (((W) & 3) * 128) + 2 * lane); \
            ++pos; } \
        if ((S) >= THsh) { \
            if (pos < CANDCAP) \
                ci[lrow][pos] = (unsigned)((((W) >> 2) * 512) + (((W) & 3) * 128) + 2 * lane + 1); \
            ++pos; } }
    CE(0, s0, q0)     CE(1, s1, q1)     CE(2, s2, q2)     CE(3, s3, q3)
    CE(4, s4, q4)     CE(5, s5, q5)     CE(6, s6, q6)     CE(7, s7, q7)
    CE(8, s8, q8)     CE(9, s9, q9)     CE(10, s10, q10)  CE(11, s11, q11)
    CE(12, s12, q12)  CE(13, s13, q13)  CE(14, s14, q14)  CE(15, s15, q15)
#undef CE

    // B) f64 rescore from f32 q,k: lane = (c8, d8); 8 cands per batch
    const int c8 = lane >> 3, d8 = lane & 7;
    const float* qrow = &qsf[lrow][d8 * 8];
    const double qd0 = (double)qrow[0], qd1 = (double)qrow[1];
    const double qd2 = (double)qrow[2], qd3 = (double)qrow[3];
    const double qd4 = (double)qrow[4], qd5 = (double)qrow[5];
    const double qd6 = (double)qrow[6], qd7 = (double)qrow[7];
    const int nb = (nc + 7) >> 3;
    for (int b = 0; b < nb; ++b) {
        const int s  = b * 8 + c8;
        const int s2 = s < nc ? s : nc - 1;
        const unsigned cidx = ci[lrow][s2];
        const unsigned kb32 = (cidx << 6) + (unsigned)(d8 * 8);
        const float2 kv0 = *(const float2*)(Kb + kb32);
        const float2 kv1 = *(const float2*)(Kb + kb32 + 2);
        const float2 kv2 = *(const float2*)(Kb + kb32 + 4);
        const float2 kv3 = *(const float2*)(Kb + kb32 + 6);
        double acc = 0.0;
        acc = fma(qd0, (double)kv0.x, acc);
        acc = fma(qd1, (double)kv0.y, acc);
        acc = fma(qd2, (double)kv1.x, acc);
        acc = fma(qd3, (double)kv1.y, acc);
        acc = fma(qd4, (double)kv2.x, acc);
        acc = fma(qd5, (double)kv2.y, acc);
        acc = fma(qd6, (double)kv3.x, acc);
        acc = fma(qd7, (double)kv3.y, acc);
        acc += __shfl_xor(acc, 1);
        acc += __shfl_xor(acc, 2);
        acc += __shfl_xor(acc, 4);
        if (d8 == 0 && s < nc) ck[lrow][s] = dkey(acc * 0.125);
    }

    // C) exact top-64 among candidates (64-bit keys, <=2 per lane)
    const unsigned long long k0 = (lane      < nc) ? ck[lrow][lane]      : 0ull;
    const unsigned long long k1 = (lane + 64 < nc) ? ck[lrow][lane + 64] : 0ull;
    const unsigned idx0 = ci[lrow][lane];
    const unsigned idx1 = ci[lrow][(lane + 64) & (CANDCAP - 1)];
    const unsigned kh0 = (unsigned)(k0 >> 32), kh1 = (unsigned)(k1 >> 32);
    const unsigned kl0 = (unsigned)k0,         kl1 = (unsigned)k1;

    // stage 1: H = hi32 of 64th-largest key
    unsigned H;
    {
        const unsigned i0 = (k0 != 0ull) ? kh0 : 0xFFFFFFFFu;
        const unsigned i1 = (k1 != 0ull) ? kh1 : 0xFFFFFFFFu;
        unsigned lo = dpp_wmin_u32(i0 < i1 ? i0 : i1);
        unsigned hi = dpp_wmax_u32(kh0 > kh1 ? kh0 : kh1);
        bool done = false;
        while (lo < hi) {
            const unsigned mid = lo + ((hi - lo) >> 1) + 1u;
            const int c = __popcll(__ballot(kh0 >= mid))
                        + __popcll(__ballot(kh1 >= mid));
            if (c == 64) {
                const unsigned v0 = (kh0 >= mid) ? kh0 : 0xFFFFFFFFu;
                const unsigned v1m = (kh1 >= mid) ? kh1 : 0xFFFFFFFFu;
                H = dpp_wmin_u32(v0 < v1m ? v0 : v1m);
                done = true; break;
            }
            if (c >= 64) lo = mid; else hi = mid - 1u;
        }
        if (!done) H = lo;
    }
    const int cGtHi = __popcll(__ballot(kh0 > H))
                    + __popcll(__ballot(kh1 > H));
    const int need1 = 64 - cGtHi;

    // stage 2: Tlo = lo32 of 64th key (need1-th largest lo32 among hi==H)
    const bool e0v = (kh0 == H) && (k0 != 0ull);
    const bool e1v = (kh1 == H) && (k1 != 0ull);
    const int cEq = __popcll(__ballot(e0v)) + __popcll(__ballot(e1v));
    unsigned Tlo;
    if (need1 == cEq) {                // all ties included -> min lo32
        const unsigned v0 = e0v ? kl0 : 0xFFFFFFFFu;
        const unsigned v1m = e1v ? kl1 : 0xFFFFFFFFu;
        Tlo = dpp_wmin_u32(v0 < v1m ? v0 : v1m);
    } else if (need1 == 1) {           // single needed -> max lo32
        const unsigned v0 = e0v ? kl0 : 0u;
        const unsigned v1m = e1v ? kl1 : 0u;
        Tlo = dpp_wmax_u32(v0 > v1m ? v0 : v1m);
    } else {
        unsigned lo = 0u, hi = 0xFFFFFFFFu;
        bool done = false;
        while (lo < hi) {
            const unsigned mid = lo + ((hi - lo) >> 1) + 1u;
            const int c = __popcll(__ballot(e0v && kl0 >= mid))
                        + __popcll(__ballot(e1v && kl1 >= mid));
            if (c == need1) {
                const unsigned v0 = (e0v && kl0 >= mid) ? kl0 : 0xFFFFFFFFu;
                const unsigned v1m = (e1v && kl1 >= mid) ? kl1 : 0xFFFFFFFFu;
                Tlo = dpp_wmin_u32(v0 < v1m ? v0 : v1m);
                done = true; break;
            }
            if (c >= need1) lo = mid; else hi = mid - 1u;
        }
        if (!done) Tlo = lo;
    }
    const unsigned long long T = ((unsigned long long)H << 32) | Tlo;

    int base = 0;                      // emit k > T as packed (f32 val, idx)
    {
        const bool g0 = k0 > T;
        unsigned long long m = __ballot(g0);
        if (g0) {
            const int pos2 = base + __popcll(m & lmask);
            wvi[lrow][pos2] = ((unsigned long long)__float_as_uint((float)dinv(k0)) << 32)
                            | (unsigned long long)idx0;
        }
        base += __popcll(m);
        const bool g1 = k1 > T;
        m = __ballot(g1);
        if (g1) {
            const int pos2 = base + __popcll(m & lmask);
            wvi[lrow][pos2] = ((unsigned long long)__float_as_uint((float)dinv(k1)) << 32)
                            | (unsigned long long)idx1;
        }
        base += __popcll(m);
    }

    int ne = 0;                        // ties k == T
    {
        const bool e0 = k0 == T;
        unsigned long long m = __ballot(e0);
        if (e0) {
            const int pos2 = ne + __popcll(m & lmask);
            if (pos2 < 64) eq_idx[lrow][pos2] = idx0;
        }
        ne += __popcll(m);
        const bool e1 = k1 == T;
        m = __ballot(e1);
        if (e1) {
            const int pos2 = ne + __popcll(m & lmask);
            if (pos2 < 64) eq_idx[lrow][pos2] = idx1;
        }
        ne += __popcll(m);
    }
    if (ne > 64) ne = 64;

    const int   need = 64 - base;
    const float tvf  = (float)dinv(T);
    if (lane < need) {                 // ties: ascending index (jax rule)
        unsigned my = 0u;
        for (int j = 0; j < ne; ++j) {
            const unsigned v = eq_idx[lrow][j];
            int rank = 0;
            for (int j2 = 0; j2 < ne; ++j2) rank += (eq_idx[lrow][j2] < v) ? 1 : 0;
            if (rank == lane) my = v;
        }
        wvi[lrow][base + lane] = ((unsigned long long)__float_as_uint(tvf) << 32)
                               | (unsigned long long)my;
    }

    // 65th element (max key < T) via 2-stage DPP max (register-only)
    const unsigned mh0 = (k0 < T) ? kh0 : 0u;
    const unsigned mh1 = (k1 < T) ? kh1 : 0u;     // invalid k=0 -> contributes 0
    const unsigned Hm = dpp_wmax_u32(mh0 > mh1 ? mh0 : mh1);
    const unsigned ml0 = (k0 < T && kh0 == Hm) ? kl0 : 0u;
    const unsigned ml1 = (k1 < T && kh1 == Hm) ? kl1 : 0u;
    const unsigned Lm = dpp_wmax_u32(ml0 > ml1 ? ml0 : ml1);
    const unsigned long long m2k = ((unsigned long long)Hm << 32) | Lm;

    int i65 = 0;
    {
        unsigned long long mm = __ballot(k0 == m2k && m2k != 0ull);
        if (mm) i65 = __shfl((int)idx0, (int)(__ffsll((long long)mm) - 1));
        else {
            mm = __ballot(k1 == m2k && m2k != 0ull);
            if (mm) i65 = __shfl((int)idx1, (int)(__ffsll((long long)mm) - 1));
        }
    }
    double fr = (dinv(T) - dinv(m2k)) * (1.0 / BLENDW);
    if (fr > 1.0) fr = 1.0;
    i65_out = i65;
    lam_out = (m2k == 0ull) ? 0.f : (float)(0.5 * (1.0 - fr));
}

// ---------------------------------------------------------------------------
// MFMA-prefiltered attn v12 (unchanged - proven 297 us): bf16 MFMA scores ->
// prefilter -> f64 recheck -> exact top-64 + rank-65 blend -> softmax + V.
// 1024 thr = 16 waves, one q-row per wave; keys in named scalars (no scratch).
// ---------------------------------------------------------------------------
__global__ __launch_bounds__(1024, 8) void attn_topk_mfma(
    const float* __restrict__ qf, const float* __restrict__ kf,
    const unsigned short* __restrict__ kbf,
    const float* __restrict__ vh, float* __restrict__ outm)
{
    // sc (16x516 f32 = 33024 B) aliased with ck (16x128 u64) + ci (16x128 u32)
    __shared__ __align__(16) char uS[33024];
    float (*sc)[516] = (float(*)[516])uS;
    unsigned long long (*ck)[CANDCAP] = (unsigned long long(*)[CANDCAP])uS;
    unsigned (*ci)[CANDCAP] = (unsigned(*)[CANDCAP])(uS + 16384);

    __shared__ float          qsf[16][68];         // f32 q rows (exact)
    __shared__ unsigned short qbf[16][72];         // bf16 q rows
    __shared__ unsigned long long wvi[16][64];     // packed (val|w, idx)
    __shared__ unsigned eq_idx[16][64];

    const int tid  = threadIdx.x;
    const int lane = tid & 63;
    const int wv   = tid >> 6;             // 0..15; wave wv owns q-row wv

    // XCD-aware bijective swizzle (grid 4096 = 8 XCDs x 512, 4096%8==0):
    // all 128 q-tiles of a slot on one XCD -> K/V stay L2-resident.
    const int wid  = (blockIdx.x & 7) * 512 + (blockIdx.x >> 3);
    const int slot = wid >> 7;             // 0..31 head slot
    const int qt   = wid & 127;
    const int bb   = slot >> 4;
    const int hh   = slot & 15;

    const float*          Qb = qf  + (size_t)slot * Nk * DHk + (size_t)qt * 16 * DHk;
    const float*          Kb = kf  + (size_t)slot * Nk * DHk;
    const unsigned short* KB = kbf + (size_t)slot * Nk * DHk;
    const float*          Vb = vh  + (size_t)slot * Nk * DHk;

    {   // stage 16 q rows: f32 + bf16 copies (1024 thr: 1 elem each)
        const int r = tid >> 6, d = tid & 63;
        const float qv = Qb[r * DHk + d];
        qsf[r][d] = qv;
        qbf[r][d] = bf16rne(qv);
    }
    __syncthreads();

    // A-fragments: A[m=lane&15][k=quad*8+j]
    const int n16  = lane & 15;
    const int quad = lane >> 4;
    short8 afrag0, afrag1;
    afrag0 = *(const short8*)&qbf[n16][quad * 8];
    afrag1 = *(const short8*)&qbf[n16][32 + quad * 8];

    // Packed hi-16 prefilter keys: 16 NAMED u32 words. Word w holds logical
    // keys {2w (lo), 2w+1 (hi)}; col(2w)=(w>>2)*512+(w&3)*128+2*lane, +1 odd.
    unsigned p0, p1, p2, p3, p4, p5, p6, p7;
    unsigned p8, p9, p10, p11, p12, p13, p14, p15;
    const int rowD = quad * 4;

    // ---- phase 1: bf16 MFMA scores, 4 chunks x 512 cols (manual unroll) ----
    // 16 waves x 2 MFMA-tiles per chunk cover the 32 ctiles. kbf is in
    // fragment-contiguous layout: tile t -> 1KB lane-linear block per half.
#define QK_TILE(CH, T, ACC) { \
    const unsigned short* kp = KB + (((CH) * 32) + (wv * 2 + (T))) * 1024 + lane * 8; \
    const short8 b0_ = *(const short8*)(kp); \
    const short8 b1_ = *(const short8*)(kp + 512); \
    ACC = __builtin_amdgcn_mfma_f32_16x16x32_bf16(afrag0, b0_, ACC, 0, 0, 0); \
    ACC = __builtin_amdgcn_mfma_f32_16x16x32_bf16(afrag1, b1_, ACC, 0, 0, 0); \
}
#define SC_STORE(T, ACC) { \
    const int ccol = (wv * 2 + (T)) * 16 + n16; \
    sc[rowD + 0][ccol] = ACC[0]; sc[rowD + 1][ccol] = ACC[1]; \
    sc[rowD + 2][ccol] = ACC[2]; sc[rowD + 3][ccol] = ACC[3]; \
}
#define PACKW(J, DEST) { \
    const float2 pr_ = *(const float2*)&sc[wv][(J) * 128 + 2 * lane]; \
    DEST = (fkey(pr_.x) >> 16) | ((fkey(pr_.y) >> 16) << 16); \
}
#define DO_CHUNK(CH, D0, D1, D2, D3) { \
    f32x4 ac0 = {0.f,0.f,0.f,0.f}, ac1 = {0.f,0.f,0.f,0.f}; \
    QK_TILE(CH, 0, ac0) QK_TILE(CH, 1, ac1) \
    __syncthreads();                   /* prev chunk's sc reads done */ \
    SC_STORE(0, ac0) SC_STORE(1, ac1) \
    __syncthreads(); \
    PACKW(0, D0) PACKW(1, D1) PACKW(2, D2) PACKW(3, D3) \
}
    DO_CHUNK(0, p0,  p1,  p2,  p3)
    DO_CHUNK(1, p4,  p5,  p6,  p7)
    DO_CHUNK(2, p8,  p9,  p10, p11)
    DO_CHUNK(3, p12, p13, p14, p15)
#undef DO_CHUNK
#undef PACKW
#undef SC_STORE
#undef QK_TILE

    __syncthreads();                       // sc dead; ck/ci alias safe

    // ---- per-row: prefilter -> f64 recheck -> exact top-64 + 65th ----
    int i65_0; float lam_0;
    proc_row(lane, wv,
             p0, p1, p2, p3, p4, p5, p6, p7,
             p8, p9, p10, p11, p12, p13, p14, p15,
             Kb, qsf, ck, ci, wvi, eq_idx, i65_0, lam_0);

    // ---- f32 softmax + V gather + boundary blend (one row per wave) ----
    {
        const unsigned long long e = wvi[wv][lane];
        const float    sv = __uint_as_float((unsigned)(e >> 32));
        const unsigned vi = (unsigned)e;
        const float mx = dpp_wmax_f32(sv);
        const float p  = __expf(sv - mx);
        const float Z  = dpp_wsum_f32(p);
        const float w  = p / Z;
        // overwrite val slot with softmax weight (wave-local row, DS in-order)
        wvi[wv][lane] = ((unsigned long long)__float_as_uint(w) << 32)
                      | (unsigned long long)vi;

        float acc = 0.f;
#pragma unroll
        for (int j = 0; j < 64; ++j) {
            const unsigned long long ej = wvi[wv][j];   // broadcast, imm offset
            const float wj = __uint_as_float((unsigned)(ej >> 32));
            const unsigned ij = (unsigned)ej;
            acc = fmaf(wj, Vb[(ij << 6) + (unsigned)lane], acc);
        }
        {   // hedge: position 63 holds the rank-64 (threshold) element
            const unsigned long long e63 = wvi[wv][63];
            const float    wT  = __uint_as_float((unsigned)(e63 >> 32));
            const unsigned i64 = (unsigned)e63;
            acc += wT * lam_0 *
                   (Vb[((unsigned)i65_0 << 6) + (unsigned)lane]
                  - Vb[(i64 << 6) + (unsigned)lane]);
        }
        const int gq = qt * 16 + wv;
        outm[((size_t)bb * Nk + gq) * Ek + hh * DHk + lane] = acc;
    }
}

// ---------------------------------------------------------------------------
extern "C" void kernel_launch(void* const* d_in, const int* in_sizes, int n_in,
                              void* d_out, int out_size, void* d_ws, size_t ws_size,
                              hipStream_t stream)
{
    const float* query = (const float*)d_in[0];
    const float* key   = (const float*)d_in[1];
    const float* value = (const float*)d_in[2];
    const float* Wq    = (const float*)d_in[3];
    const float* bq    = (const float*)d_in[4];
    const float* Wk    = (const float*)d_in[5];
    const float* bk    = (const float*)d_in[6];
    const float* Wv    = (const float*)d_in[7];
    const float* bv    = (const float*)d_in[8];
    const float* Wo    = (const float*)d_in[9];
    const float* bo    = (const float*)d_in[10];
    float* out = (float*)d_out;
    (void)in_sizes; (void)n_in; (void)out_size; (void)ws_size;

    // 92 MB (ws >= 96 MB proven): qf|kf|v|attn f32 (16 MB ea) + kbf (8) +
    // xh|xl (8 ea, reused per GEMM) + wh|wl (2 ea, reused)
    const size_t seg  = (size_t)(Bk * Hk) * Nk * DHk;   // 4M elems
    const size_t wseg = (size_t)Ek * Ek;                 // 1M elems
    float* qfp = (float*)d_ws;
    float* kfp = qfp + seg;
    float* vws = kfp + seg;
    float* aws = vws + seg;
    unsigned short* kbf = (unsigned short*)(aws + seg);
    unsigned short* xh  = kbf + seg;
    unsigned short* xl  = xh + seg;
    unsigned short* wh  = xl + seg;
    unsigned short* wl  = wh + wseg;

    const dim3 blk(256);
    const dim3 gG(16, 64);                 // gemm grid: N/64 x M/64 = 1024
    const int  gX = (int)(seg  / 2048);    // cvt grid segments
    const int  gW = (int)(wseg / 2048);
    const dim3 gC(gX + gW);                // merged cvt grid

    // Q projection
    hipLaunchKernelGGL(cvt_split2, gC, blk, 0, stream, query, xh, xl, gX, Wq, wh, wl);
    hipLaunchKernelGGL((gemm_mfma<1>), gG, blk, 0, stream, xh, xl, wh, wl, bq, qfp, (unsigned short*)nullptr);
    // K projection (+ fused bf16 fragment-layout output for prefilter)
    hipLaunchKernelGGL(cvt_split2, gC, blk, 0, stream, key, xh, xl, gX, Wk, wh, wl);
    hipLaunchKernelGGL((gemm_mfma<1>), gG, blk, 0, stream, xh, xl, wh, wl, bk, kfp, kbf);
    // V projection
    hipLaunchKernelGGL(cvt_split2, gC, blk, 0, stream, value, xh, xl, gX, Wv, wh, wl);
    hipLaunchKernelGGL((gemm_mfma<1>), gG, blk, 0, stream, xh, xl, wh, wl, bv, vws, (unsigned short*)nullptr);
    // Attention
    hipLaunchKernelGGL(attn_topk_mfma, dim3(32 * 128), dim3(1024), 0, stream,
                       qfp, kfp, kbf, vws, aws);
    // Output projection
    hipLaunchKernelGGL(cvt_split2, gC, blk, 0, stream, aws, xh, xl, gX, Wo, wh, wl);
    hipLaunchKernelGGL((gemm_mfma<0>), gG, blk, 0, stream, xh, xl, wh, wl, bo, out, (unsigned short*)nullptr);
}

// Round 11
// 535.538 us; speedup vs baseline: 1.0682x; 1.0682x over previous
//
#include <hip/hip_runtime.h>
#include <stdint.h>
#include <math.h>

#define Bk 2
#define Nk 2048
#define Ek 1024
#define Hk 16
#define DHk 64
#define BLENDW 5e-5    // blend ramp width on scaled-score gap
#define PRECAND 96     // prefilter count target (>=65 + margin)
#define CANDCAP 128

using short8 = __attribute__((ext_vector_type(8))) short;
using f32x4  = __attribute__((ext_vector_type(4))) float;

__device__ __forceinline__ unsigned short bf16rne(float f) {
    const unsigned u = __float_as_uint(f);
    return (unsigned short)((u + 0x7FFFu + ((u >> 16) & 1u)) >> 16);
}

// ---------------------------------------------------------------------------
// f32 -> (hi bf16, lo bf16) split: x ~= hi + lo, rel err ~2^-17.
// Two segments (X and W) in ONE launch - halves cvt launch count.
// ---------------------------------------------------------------------------
__global__ __launch_bounds__(256) void cvt_split2(
    const float* __restrict__ inA, unsigned short* __restrict__ ohA,
    unsigned short* __restrict__ olA, int nA,
    const float* __restrict__ inB, unsigned short* __restrict__ ohB,
    unsigned short* __restrict__ olB)
{
    const int b = blockIdx.x;
    const float* in; unsigned short* oh; unsigned short* ol; int i;
    if (b < nA) { in = inA; oh = ohA; ol = olA; i = b * 256 + threadIdx.x; }
    else        { in = inB; oh = ohB; ol = olB; i = (b - nA) * 256 + threadIdx.x; }

    const float4 a = ((const float4*)in)[i * 2];
    const float4 c = ((const float4*)in)[i * 2 + 1];
    float x[8] = {a.x, a.y, a.z, a.w, c.x, c.y, c.z, c.w};
    unsigned short hs[8], ls[8];
#pragma unroll
    for (int j = 0; j < 8; ++j) {
        hs[j] = bf16rne(x[j]);
        const float hf = __uint_as_float((unsigned)hs[j] << 16);
        ls[j] = bf16rne(x[j] - hf);
    }
    uint4 ho, lo;
    ho.x = hs[0] | ((unsigned)hs[1] << 16); ho.y = hs[2] | ((unsigned)hs[3] << 16);
    ho.z = hs[4] | ((unsigned)hs[5] << 16); ho.w = hs[6] | ((unsigned)hs[7] << 16);
    lo.x = ls[0] | ((unsigned)ls[1] << 16); lo.y = ls[2] | ((unsigned)ls[3] << 16);
    lo.z = ls[4] | ((unsigned)ls[5] << 16); lo.w = ls[6] | ((unsigned)ls[7] << 16);
    ((uint4*)oh)[i] = ho;
    ((uint4*)ol)[i] = lo;
}

// ---------------------------------------------------------------------------
// Split-bf16 MFMA GEMM: C[m,c] = sum_k X[m,k]W[c,k] + bias[c]
//   = Xh*Wh + Xh*Wl + Xl*Wh  (3 MFMA per k-tile; rel err ~2^-17 < f32 GEMM)
// v14: back to proven 128x64 tile (r10's 64x64 halved MFMA-per-barrier, -14us)
// + XCD-AWARE GRID SWIZZLE: 1D grid 512 = 8 XCDs x 64; each XCD owns 4
// contiguous row-panels x 16 col-blocks. Default round-robin made every X
// row-panel fetched by all 8 XCDs (~160 MB/GEMM); swizzled: X fetched once
// per panel (~50 MB/GEMM). Bijective (512%8==0).
// MODE 0: out[m*Ek+c]; MODE 1: split-head f32 out; obf != null -> bf16 copy in
// FRAGMENT-CONTIGUOUS layout (verified r8): short_off = (nn>>4)*1024 +
// (dd>>5)*512 + ((((dd>>3)&3)*16 + (nn&15))*8) + (dd&7).
// ---------------------------------------------------------------------------
template<int MODE>
__global__ __launch_bounds__(256, 4) void gemm_mfma(
    const unsigned short* __restrict__ Xh, const unsigned short* __restrict__ Xl,
    const unsigned short* __restrict__ Wh, const unsigned short* __restrict__ Wl,
    const float* __restrict__ bias, float* __restrict__ out,
    unsigned short* __restrict__ obf)
{
    __shared__ unsigned short Ah[128][40], Al[128][40];   // [m][k] pad->80B rows
    __shared__ unsigned short Bh[64][40],  Bl[64][40];    // [c][k]

    const int tid  = threadIdx.x;
    const int lane = tid & 63;
    const int wv   = tid >> 6;
    const int n16  = lane & 15;
    const int quad = lane >> 4;

    // XCD swizzle: bid%8 = XCD -> give it 64 consecutive row-major blocks
    const int bid = blockIdx.x;                    // 0..511
    const int wid = (bid & 7) * 64 + (bid >> 3);   // bijective remap
    const int mBase = (wid >> 4) * 128;            // row-panel 0..31
    const int nBase = (wid & 15) * 64;             // col-block 0..15

    f32x4 acc[2][4];
#pragma unroll
    for (int i = 0; i < 2; ++i)
#pragma unroll
        for (int j = 0; j < 4; ++j) acc[i][j] = (f32x4){0.f, 0.f, 0.f, 0.f};

    const int arow = tid >> 1, aoff = (tid & 1) * 16;   // A: 16 shorts/thread
    const int brow = tid >> 2, boff = (tid & 3) * 8;    // B: 8 shorts/thread
    const size_t aIdx = (size_t)(mBase + arow) * Ek + aoff;
    const size_t bIdx = (size_t)(nBase + brow) * Ek + boff;

    for (int kt = 0; kt < Ek; kt += 32) {
        const uint4 ah0 = *(const uint4*)(Xh + aIdx + kt);
        const uint4 ah1 = *(const uint4*)(Xh + aIdx + kt + 8);
        const uint4 al0 = *(const uint4*)(Xl + aIdx + kt);
        const uint4 al1 = *(const uint4*)(Xl + aIdx + kt + 8);
        const uint4 bh0 = *(const uint4*)(Wh + bIdx + kt);
        const uint4 bl0 = *(const uint4*)(Wl + bIdx + kt);
        __syncthreads();
        *(uint4*)&Ah[arow][aoff]     = ah0;
        *(uint4*)&Ah[arow][aoff + 8] = ah1;
        *(uint4*)&Al[arow][aoff]     = al0;
        *(uint4*)&Al[arow][aoff + 8] = al1;
        *(uint4*)&Bh[brow][boff]     = bh0;
        *(uint4*)&Bl[brow][boff]     = bl0;
        __syncthreads();

        const short8 fa_h0 = *(const short8*)&Ah[wv*32 +      n16][quad*8];
        const short8 fa_l0 = *(const short8*)&Al[wv*32 +      n16][quad*8];
        const short8 fa_h1 = *(const short8*)&Ah[wv*32 + 16 + n16][quad*8];
        const short8 fa_l1 = *(const short8*)&Al[wv*32 + 16 + n16][quad*8];
#pragma unroll
        for (int ct = 0; ct < 4; ++ct) {
            const short8 fb_h = *(const short8*)&Bh[ct*16 + n16][quad*8];
            const short8 fb_l = *(const short8*)&Bl[ct*16 + n16][quad*8];
            acc[0][ct] = __builtin_amdgcn_mfma_f32_16x16x32_bf16(fa_h0, fb_h, acc[0][ct], 0, 0, 0);
            acc[0][ct] = __builtin_amdgcn_mfma_f32_16x16x32_bf16(fa_h0, fb_l, acc[0][ct], 0, 0, 0);
            acc[0][ct] = __builtin_amdgcn_mfma_f32_16x16x32_bf16(fa_l0, fb_h, acc[0][ct], 0, 0, 0);
            acc[1][ct] = __builtin_amdgcn_mfma_f32_16x16x32_bf16(fa_h1, fb_h, acc[1][ct], 0, 0, 0);
            acc[1][ct] = __builtin_amdgcn_mfma_f32_16x16x32_bf16(fa_h1, fb_l, acc[1][ct], 0, 0, 0);
            acc[1][ct] = __builtin_amdgcn_mfma_f32_16x16x32_bf16(fa_l1, fb_h, acc[1][ct], 0, 0, 0);
        }
    }

    // epilogue: D row = quad*4+reg (within 16-tile), col = n16
#pragma unroll
    for (int mt = 0; mt < 2; ++mt)
#pragma unroll
    for (int ct = 0; ct < 4; ++ct) {
        const int c  = nBase + ct*16 + n16;
        const float bv = bias[c];
#pragma unroll
        for (int reg = 0; reg < 4; ++reg) {
            const int m = mBase + wv*32 + mt*16 + quad*4 + reg;
            const float o = acc[mt][ct][reg] + bv;
            if (MODE == 0) {
                out[(size_t)m * Ek + c] = o;
            } else {
                const int bb2 = m >> 11, nn = m & 2047;
                const int hh2 = c >> 6,  dd = c & 63;
                const size_t sb = (size_t)(bb2*Hk + hh2) * Nk * DHk;
                out[sb + (size_t)nn * DHk + dd] = o;
                if (obf) {
                    const size_t kdst = sb + (size_t)(nn >> 4) * 1024
                                      + ((dd >> 5) * 512)
                                      + ((((dd >> 3) & 3) * 16 + (nn & 15)) * 8)
                                      + (dd & 7);
                    obf[kdst] = bf16rne(o);
                }
            }
        }
    }
}

// ---------------------------------------------------------------------------
__device__ __forceinline__ unsigned fkey(float s) {
    const unsigned b = __float_as_uint(s);
    return (b & 0x80000000u) ? ~b : (b | 0x80000000u);
}
__device__ __forceinline__ unsigned long long dkey(double s) {
    unsigned long long b = (unsigned long long)__double_as_longlong(s);
    return (b & 0x8000000000000000ull) ? ~b : (b | 0x8000000000000000ull);
}
__device__ __forceinline__ double dinv(unsigned long long u) {
    const unsigned long long b =
        (u & 0x8000000000000000ull) ? (u & 0x7fffffffffffffffull) : ~u;
    return __longlong_as_double((long long)b);
}

// ---------------------------------------------------------------------------
// DPP wave-64 reductions / scan (rocPRIM & LLVM AtomicOptimizer patterns).
// ---------------------------------------------------------------------------
__device__ __forceinline__ int dpp_wsum_i32(int x) {
#define STEP(C) x += __builtin_amdgcn_update_dpp(0, x, C, 0xf, 0xf, true);
    STEP(0x111) STEP(0x112) STEP(0x114) STEP(0x118) STEP(0x142) STEP(0x143)
#undef STEP
    return __builtin_amdgcn_readlane(x, 63);
}
__device__ __forceinline__ float dpp_wsum_f32(float x) {
#define STEP(C) { const int t_ = __builtin_amdgcn_update_dpp(0, __float_as_int(x), C, 0xf, 0xf, true); \
                  x += __int_as_float(t_); }
    STEP(0x111) STEP(0x112) STEP(0x114) STEP(0x118) STEP(0x142) STEP(0x143)
#undef STEP
    return __int_as_float(__builtin_amdgcn_readlane(__float_as_int(x), 63));
}
__device__ __forceinline__ float dpp_wmax_f32(float x) {
#define STEP(C) { const int t_ = __builtin_amdgcn_update_dpp(__float_as_int(x), __float_as_int(x), C, 0xf, 0xf, false); \
                  x = fmaxf(x, __int_as_float(t_)); }
    STEP(0x111) STEP(0x112) STEP(0x114) STEP(0x118) STEP(0x142) STEP(0x143)
#undef STEP
    return __int_as_float(__builtin_amdgcn_readlane(__float_as_int(x), 63));
}
__device__ __forceinline__ unsigned dpp_wmin_u32(unsigned x) {
#define STEP(C) { const unsigned t_ = (unsigned)__builtin_amdgcn_update_dpp((int)x, (int)x, C, 0xf, 0xf, false); \
                  x = x < t_ ? x : t_; }
    STEP(0x111) STEP(0x112) STEP(0x114) STEP(0x118) STEP(0x142) STEP(0x143)
#undef STEP
    return (unsigned)__builtin_amdgcn_readlane((int)x, 63);
}
__device__ __forceinline__ unsigned dpp_wmax_u32(unsigned x) {
#define STEP(C) { const unsigned t_ = (unsigned)__builtin_amdgcn_update_dpp((int)x, (int)x, C, 0xf, 0xf, false); \
                  x = x > t_ ? x : t_; }
    STEP(0x111) STEP(0x112) STEP(0x114) STEP(0x118) STEP(0x142) STEP(0x143)
#undef STEP
    return (unsigned)__builtin_amdgcn_readlane((int)x, 63);
}
// inclusive prefix-sum across 64 lanes (LLVM buildScan pattern)
__device__ __forceinline__ int dpp_wprefix_incl_i32(int x) {
    x += __builtin_amdgcn_update_dpp(0, x, 0x111, 0xf, 0xf, true);  // row_shr:1
    x += __builtin_amdgcn_update_dpp(0, x, 0x112, 0xf, 0xf, true);  // row_shr:2
    x += __builtin_amdgcn_update_dpp(0, x, 0x114, 0xf, 0xf, true);  // row_shr:4
    x += __builtin_amdgcn_update_dpp(0, x, 0x118, 0xf, 0xf, true);  // row_shr:8
    x += __builtin_amdgcn_update_dpp(0, x, 0x142, 0xa, 0xf, true);  // bcast15 -> rows 1,3
    x += __builtin_amdgcn_update_dpp(0, x, 0x143, 0xc, 0xf, true);  // bcast31 -> rows 2,3
    return x;
}

// ---------------------------------------------------------------------------
// Per-row top-k: prefilter -> f64 recheck -> exact top-64 + rank-65 blend.
// (unchanged - proven 295 us)
// ---------------------------------------------------------------------------
__device__ __forceinline__ void proc_row(
    const int lane, const int lrow,
    unsigned s0, unsigned s1, unsigned s2, unsigned s3,
    unsigned s4, unsigned s5, unsigned s6, unsigned s7,
    unsigned s8, unsigned s9, unsigned s10, unsigned s11,
    unsigned s12, unsigned s13, unsigned s14, unsigned s15,
    const float* __restrict__ Kb, const float (*qsf)[68],
    unsigned long long (*ck)[CANDCAP], unsigned (*ci)[CANDCAP],
    unsigned long long (*wvi)[64], unsigned (*eq_idx)[64],
    int& i65_out, float& lam_out)
{
    const unsigned long long lmask = (1ull << lane) - 1ull;

    // shifted copies: q_w = lo-half in compare space (hi-half compares use s_w)
    const unsigned q0 = s0 << 16,  q1 = s1 << 16,  q2 = s2 << 16,  q3 = s3 << 16;
    const unsigned q4 = s4 << 16,  q5 = s5 << 16,  q6 = s6 << 16,  q7 = s7 << 16;
    const unsigned q8 = s8 << 16,  q9 = s9 << 16,  q10 = s10 << 16, q11 = s11 << 16;
    const unsigned q12 = s12 << 16, q13 = s13 << 16, q14 = s14 << 16, q15 = s15 << 16;

    // A) bracket: per-lane top-2 over the 32 junk-space values.
    unsigned m1 = 0u, m2 = 0u;
#define T2(V) { const unsigned t_ = (V) < m1 ? (V) : m1; \
                m1 = m1 > (V) ? m1 : (V);  m2 = m2 > t_ ? m2 : t_; }
    T2(s0)  T2(s1)  T2(s2)  T2(s3)  T2(s4)  T2(s5)  T2(s6)  T2(s7)
    T2(s8)  T2(s9)  T2(s10) T2(s11) T2(s12) T2(s13) T2(s14) T2(s15)
    T2(q0)  T2(q1)  T2(q2)  T2(q3)  T2(q4)  T2(q5)  T2(q6)  T2(q7)
    T2(q8)  T2(q9)  T2(q10) T2(q11) T2(q12) T2(q13) T2(q14) T2(q15)
#undef T2
    unsigned lo16 = dpp_wmin_u32(m2) >> 16;   // count(>=lo16) >= 2/lane -> >=128
    unsigned hi16 = dpp_wmax_u32(m1) >> 16;   // count(>=hi16+1) == 0

    // binary search: largest TH with count >= PRECAND; window-accept [96,128]
    while (lo16 < hi16) {
        const unsigned mid = lo16 + ((hi16 - lo16) >> 1) + 1u;
        const unsigned M = mid << 16;
        int c0 = 0, c1 = 0, c2 = 0, c3 = 0;    // 4 accums: break dep chain
        c0 += (s0  >= M); c0 += (q0  >= M); c0 += (s1  >= M); c0 += (q1  >= M);
        c0 += (s2  >= M); c0 += (q2  >= M); c0 += (s3  >= M); c0 += (q3  >= M);
        c1 += (s4  >= M); c1 += (q4  >= M); c1 += (s5  >= M); c1 += (q5  >= M);
        c1 += (s6  >= M); c1 += (q6  >= M); c1 += (s7  >= M); c1 += (q7  >= M);
        c2 += (s8  >= M); c2 += (q8  >= M); c2 += (s9  >= M); c2 += (q9  >= M);
        c2 += (s10 >= M); c2 += (q10 >= M); c2 += (s11 >= M); c2 += (q11 >= M);
        c3 += (s12 >= M); c3 += (q12 >= M); c3 += (s13 >= M); c3 += (q13 >= M);
        c3 += (s14 >= M); c3 += (q14 >= M); c3 += (s15 >= M); c3 += (q15 >= M);
        const int c = dpp_wsum_i32((c0 + c1) + (c2 + c3));
        if (c >= PRECAND) {
            lo16 = mid;
            if (c <= CANDCAP) break;       // window accept (superset-safe)
        } else hi16 = mid - 1u;
    }
    const unsigned THsh = lo16 << 16;

    // collect candidates, LANE-MAJOR: per-lane count -> DPP prefix -> scatter
    int cnt = 0;
#define CC(S, Q) { cnt += ((Q) >= THsh); cnt += ((S) >= THsh); }
    CC(s0, q0)    CC(s1, q1)    CC(s2, q2)    CC(s3, q3)
    CC(s4, q4)    CC(s5, q5)    CC(s6, q6)    CC(s7, q7)
    CC(s8, q8)    CC(s9, q9)    CC(s10, q10)  CC(s11, q11)
    CC(s12, q12)  CC(s13, q13)  CC(s14, q14)  CC(s15, q15)
#undef CC
    const int incl = dpp_wprefix_incl_i32(cnt);
    int pos = incl - cnt;                       // exclusive prefix
    int nc = __builtin_amdgcn_readlane(incl, 63);
    if (nc > CANDCAP) nc = CANDCAP;
#define CE(W, S, Q) { \
        if ((Q) >= THsh) { \
            if (pos < CANDCAP) \
                ci[lrow][pos] = (unsigned)((((W) >> 2) * 512) + (((W) & 3) * 128) + 2 * lane); \
            ++pos; } \
        if ((S) >= THsh) { \
            if (pos < CANDCAP) \
                ci[lrow][pos] = (unsigned)((((W) >> 2) * 512) + (((W) & 3) * 128) + 2 * lane + 1); \
            ++pos; } }
    CE(0, s0, q0)     CE(1, s1, q1)     CE(2, s2, q2)     CE(3, s3, q3)
    CE(4, s4, q4)     CE(5, s5, q5)     CE(6, s6, q6)     CE(7, s7, q7)
    CE(8, s8, q8)     CE(9, s9, q9)     CE(10, s10, q10)  CE(11, s11, q11)
    CE(12, s12, q12)  CE(13, s13, q13)  CE(14, s14, q14)  CE(15, s15, q15)
#undef CE

    // B) f64 rescore from f32 q,k: lane = (c8, d8); 8 cands per batch
    const int c8 = lane >> 3, d8 = lane & 7;
    const float* qrow = &qsf[lrow][d8 * 8];
    const double qd0 = (double)qrow[0], qd1 = (double)qrow[1];
    const double qd2 = (double)qrow[2], qd3 = (double)qrow[3];
    const double qd4 = (double)qrow[4], qd5 = (double)qrow[5];
    const double qd6 = (double)qrow[6], qd7 = (double)qrow[7];
    const int nb = (nc + 7) >> 3;
    for (int b = 0; b < nb; ++b) {
        const int s  = b * 8 + c8;
        const int s2 = s < nc ? s : nc - 1;
        const unsigned cidx = ci[lrow][s2];
        const unsigned kb32 = (cidx << 6) + (unsigned)(d8 * 8);
        const float2 kv0 = *(const float2*)(Kb + kb32);
        const float2 kv1 = *(const float2*)(Kb + kb32 + 2);
        const float2 kv2 = *(const float2*)(Kb + kb32 + 4);
        const float2 kv3 = *(const float2*)(Kb + kb32 + 6);
        double acc = 0.0;
        acc = fma(qd0, (double)kv0.x, acc);
        acc = fma(qd1, (double)kv0.y, acc);
        acc = fma(qd2, (double)kv1.x, acc);
        acc = fma(qd3, (double)kv1.y, acc);
        acc = fma(qd4, (double)kv2.x, acc);
        acc = fma(qd5, (double)kv2.y, acc);
        acc = fma(qd6, (double)kv3.x, acc);
        acc = fma(qd7, (double)kv3.y, acc);
        acc += __shfl_xor(acc, 1);
        acc += __shfl_xor(acc, 2);
        acc += __shfl_xor(acc, 4);
        if (d8 == 0 && s < nc) ck[lrow][s] = dkey(acc * 0.125);
    }

    // C) exact top-64 among candidates (64-bit keys, <=2 per lane)
    const unsigned long long k0 = (lane      < nc) ? ck[lrow][lane]      : 0ull;
    const unsigned long long k1 = (lane + 64 < nc) ? ck[lrow][lane + 64] : 0ull;
    const unsigned idx0 = ci[lrow][lane];
    const unsigned idx1 = ci[lrow][(lane + 64) & (CANDCAP - 1)];
    const unsigned kh0 = (unsigned)(k0 >> 32), kh1 = (unsigned)(k1 >> 32);
    const unsigned kl0 = (unsigned)k0,         kl1 = (unsigned)k1;

    // stage 1: H = hi32 of 64th-largest key
    unsigned H;
    {
        const unsigned i0 = (k0 != 0ull) ? kh0 : 0xFFFFFFFFu;
        const unsigned i1 = (k1 != 0ull) ? kh1 : 0xFFFFFFFFu;
        unsigned lo = dpp_wmin_u32(i0 < i1 ? i0 : i1);
        unsigned hi = dpp_wmax_u32(kh0 > kh1 ? kh0 : kh1);
        bool done = false;
        while (lo < hi) {
            const unsigned mid = lo + ((hi - lo) >> 1) + 1u;
            const int c = __popcll(__ballot(kh0 >= mid))
                        + __popcll(__ballot(kh1 >= mid));
            if (c == 64) {
                const unsigned v0 = (kh0 >= mid) ? kh0 : 0xFFFFFFFFu;
                const unsigned v1m = (kh1 >= mid) ? kh1 : 0xFFFFFFFFu;
                H = dpp_wmin_u32(v0 < v1m ? v0 : v1m);
                done = true; break;
            }
            if (c >= 64) lo = mid; else hi = mid - 1u;
        }
        if (!done) H = lo;
    }
    const int cGtHi = __popcll(__ballot(kh0 > H))
                    + __popcll(__ballot(kh1 > H));
    const int need1 = 64 - cGtHi;

    // stage 2: Tlo = lo32 of 64th key (need1-th largest lo32 among hi==H)
    const bool e0v = (kh0 == H) && (k0 != 0ull);
    const bool e1v = (kh1 == H) && (k1 != 0ull);
    const int cEq = __popcll(__ballot(e0v)) + __popcll(__ballot(e1v));
    unsigned Tlo;
    if (need1 == cEq) {                // all ties included -> min lo32
        const unsigned v0 = e0v ? kl0 : 0xFFFFFFFFu;
        const unsigned v1m = e1v ? kl1 : 0xFFFFFFFFu;
        Tlo = dpp_wmin_u32(v0 < v1m ? v0 : v1m);
    } else if (need1 == 1) {           // single needed -> max lo32
        const unsigned v0 = e0v ? kl0 : 0u;
        const unsigned v1m = e1v ? kl1 : 0u;
        Tlo = dpp_wmax_u32(v0 > v1m ? v0 : v1m);
    } else {
        unsigned lo = 0u, hi = 0xFFFFFFFFu;
        bool done = false;
        while (lo < hi) {
            const unsigned mid = lo + ((hi - lo) >> 1) + 1u;
            const int c = __popcll(__ballot(e0v && kl0 >= mid))
                        + __popcll(__ballot(e1v && kl1 >= mid));
            if (c == need1) {
                const unsigned v0 = (e0v && kl0 >= mid) ? kl0 : 0xFFFFFFFFu;
                const unsigned v1m = (e1v && kl1 >= mid) ? kl1 : 0xFFFFFFFFu;
                Tlo = dpp_wmin_u32(v0 < v1m ? v0 : v1m);
                done = true; break;
            }
            if (c >= need1) lo = mid; else hi = mid - 1u;
        }
        if (!done) Tlo = lo;
    }
    const unsigned long long T = ((unsigned long long)H << 32) | Tlo;

    int base = 0;                      // emit k > T as packed (f32 val, idx)
    {
        const bool g0 = k0 > T;
        unsigned long long m = __ballot(g0);
        if (g0) {
            const int pos2 = base + __popcll(m & lmask);
            wvi[lrow][pos2] = ((unsigned long long)__float_as_uint((float)dinv(k0)) << 32)
                            | (unsigned long long)idx0;
        }
        base += __popcll(m);
        const bool g1 = k1 > T;
        m = __ballot(g1);
        if (g1) {
            const int pos2 = base + __popcll(m & lmask);
            wvi[lrow][pos2] = ((unsigned long long)__float_as_uint((float)dinv(k1)) << 32)
                            | (unsigned long long)idx1;
        }
        base += __popcll(m);
    }

    int ne = 0;                        // ties k == T
    {
        const bool e0 = k0 == T;
        unsigned long long m = __ballot(e0);
        if (e0) {
            const int pos2 = ne + __popcll(m & lmask);
            if (pos2 < 64) eq_idx[lrow][pos2] = idx0;
        }
        ne += __popcll(m);
        const bool e1 = k1 == T;
        m = __ballot(e1);
        if (e1) {
            const int pos2 = ne + __popcll(m & lmask);
            if (pos2 < 64) eq_idx[lrow][pos2] = idx1;
        }
        ne += __popcll(m);
    }
    if (ne > 64) ne = 64;

    const int   need = 64 - base;
    const float tvf  = (float)dinv(T);
    if (lane < need) {                 // ties: ascending index (jax rule)
        unsigned my = 0u;
        for (int j = 0; j < ne; ++j) {
            const unsigned v = eq_idx[lrow][j];
            int rank = 0;
            for (int j2 = 0; j2 < ne; ++j2) rank += (eq_idx[lrow][j2] < v) ? 1 : 0;
            if (rank == lane) my = v;
        }
        wvi[lrow][base + lane] = ((unsigned long long)__float_as_uint(tvf) << 32)
                               | (unsigned long long)my;
    }

    // 65th element (max key < T) via 2-stage DPP max (register-only)
    const unsigned mh0 = (k0 < T) ? kh0 : 0u;
    const unsigned mh1 = (k1 < T) ? kh1 : 0u;     // invalid k=0 -> contributes 0
    const unsigned Hm = dpp_wmax_u32(mh0 > mh1 ? mh0 : mh1);
    const unsigned ml0 = (k0 < T && kh0 == Hm) ? kl0 : 0u;
    const unsigned ml1 = (k1 < T && kh1 == Hm) ? kl1 : 0u;
    const unsigned Lm = dpp_wmax_u32(ml0 > ml1 ? ml0 : ml1);
    const unsigned long long m2k = ((unsigned long long)Hm << 32) | Lm;

    int i65 = 0;
    {
        unsigned long long mm = __ballot(k0 == m2k && m2k != 0ull);
        if (mm) i65 = __shfl((int)idx0, (int)(__ffsll((long long)mm) - 1));
        else {
            mm = __ballot(k1 == m2k && m2k != 0ull);
            if (mm) i65 = __shfl((int)idx1, (int)(__ffsll((long long)mm) - 1));
        }
    }
    double fr = (dinv(T) - dinv(m2k)) * (1.0 / BLENDW);
    if (fr > 1.0) fr = 1.0;
    i65_out = i65;
    lam_out = (m2k == 0ull) ? 0.f : (float)(0.5 * (1.0 - fr));
}

// ---------------------------------------------------------------------------
// MFMA-prefiltered attn (unchanged - proven 295 us): bf16 MFMA scores ->
// prefilter -> f64 recheck -> exact top-64 + rank-65 blend -> softmax + V.
// 1024 thr = 16 waves, one q-row per wave; keys in named scalars (no scratch).
// ---------------------------------------------------------------------------
__global__ __launch_bounds__(1024, 8) void attn_topk_mfma(
    const float* __restrict__ qf, const float* __restrict__ kf,
    const unsigned short* __restrict__ kbf,
    const float* __restrict__ vh, float* __restrict__ outm)
{
    // sc (16x516 f32 = 33024 B) aliased with ck (16x128 u64) + ci (16x128 u32)
    __shared__ __align__(16) char uS[33024];
    float (*sc)[516] = (float(*)[516])uS;
    unsigned long long (*ck)[CANDCAP] = (unsigned long long(*)[CANDCAP])uS;
    unsigned (*ci)[CANDCAP] = (unsigned(*)[CANDCAP])(uS + 16384);

    __shared__ float          qsf[16][68];         // f32 q rows (exact)
    __shared__ unsigned short qbf[16][72];         // bf16 q rows
    __shared__ unsigned long long wvi[16][64];     // packed (val|w, idx)
    __shared__ unsigned eq_idx[16][64];

    const int tid  = threadIdx.x;
    const int lane = tid & 63;
    const int wv   = tid >> 6;             // 0..15; wave wv owns q-row wv

    // XCD-aware bijective swizzle (grid 4096 = 8 XCDs x 512, 4096%8==0):
    // all 128 q-tiles of a slot on one XCD -> K/V stay L2-resident.
    const int wid  = (blockIdx.x & 7) * 512 + (blockIdx.x >> 3);
    const int slot = wid >> 7;             // 0..31 head slot
    const int qt   = wid & 127;
    const int bb   = slot >> 4;
    const int hh   = slot & 15;

    const float*          Qb = qf  + (size_t)slot * Nk * DHk + (size_t)qt * 16 * DHk;
    const float*          Kb = kf  + (size_t)slot * Nk * DHk;
    const unsigned short* KB = kbf + (size_t)slot * Nk * DHk;
    const float*          Vb = vh  + (size_t)slot * Nk * DHk;

    {   // stage 16 q rows: f32 + bf16 copies (1024 thr: 1 elem each)
        const int r = tid >> 6, d = tid & 63;
        const float qv = Qb[r * DHk + d];
        qsf[r][d] = qv;
        qbf[r][d] = bf16rne(qv);
    }
    __syncthreads();

    // A-fragments: A[m=lane&15][k=quad*8+j]
    const int n16  = lane & 15;
    const int quad = lane >> 4;
    short8 afrag0, afrag1;
    afrag0 = *(const short8*)&qbf[n16][quad * 8];
    afrag1 = *(const short8*)&qbf[n16][32 + quad * 8];

    // Packed hi-16 prefilter keys: 16 NAMED u32 words. Word w holds logical
    // keys {2w (lo), 2w+1 (hi)}; col(2w)=(w>>2)*512+(w&3)*128+2*lane, +1 odd.
    unsigned p0, p1, p2, p3, p4, p5, p6, p7;
    unsigned p8, p9, p10, p11, p12, p13, p14, p15;
    const int rowD = quad * 4;

    // ---- phase 1: bf16 MFMA scores, 4 chunks x 512 cols (manual unroll) ----
    // 16 waves x 2 MFMA-tiles per chunk cover the 32 ctiles. kbf is in
    // fragment-contiguous layout: tile t -> 1KB lane-linear block per half.
#define QK_TILE(CH, T, ACC) { \
    const unsigned short* kp = KB + (((CH) * 32) + (wv * 2 + (T))) * 1024 + lane * 8; \
    const short8 b0_ = *(const short8*)(kp); \
    const short8 b1_ = *(const short8*)(kp + 512); \
    ACC = __builtin_amdgcn_mfma_f32_16x16x32_bf16(afrag0, b0_, ACC, 0, 0, 0); \
    ACC = __builtin_amdgcn_mfma_f32_16x16x32_bf16(afrag1, b1_, ACC, 0, 0, 0); \
}
#define SC_STORE(T, ACC) { \
    const int ccol = (wv * 2 + (T)) * 16 + n16; \
    sc[rowD + 0][ccol] = ACC[0]; sc[rowD + 1][ccol] = ACC[1]; \
    sc[rowD + 2][ccol] = ACC[2]; sc[rowD + 3][ccol] = ACC[3]; \
}
#define PACKW(J, DEST) { \
    const float2 pr_ = *(const float2*)&sc[wv][(J) * 128 + 2 * lane]; \
    DEST = (fkey(pr_.x) >> 16) | ((fkey(pr_.y) >> 16) << 16); \
}
#define DO_CHUNK(CH, D0, D1, D2, D3) { \
    f32x4 ac0 = {0.f,0.f,0.f,0.f}, ac1 = {0.f,0.f,0.f,0.f}; \
    QK_TILE(CH, 0, ac0) QK_TILE(CH, 1, ac1) \
    __syncthreads();                   /* prev chunk's sc reads done */ \
    SC_STORE(0, ac0) SC_STORE(1, ac1) \
    __syncthreads(); \
    PACKW(0, D0) PACKW(1, D1) PACKW(2, D2) PACKW(3, D3) \
}
    DO_CHUNK(0, p0,  p1,  p2,  p3)
    DO_CHUNK(1, p4,  p5,  p6,  p7)
    DO_CHUNK(2, p8,  p9,  p10, p11)
    DO_CHUNK(3, p12, p13, p14, p15)
#undef DO_CHUNK
#undef PACKW
#undef SC_STORE
#undef QK_TILE

    __syncthreads();                       // sc dead; ck/ci alias safe

    // ---- per-row: prefilter -> f64 recheck -> exact top-64 + 65th ----
    int i65_0; float lam_0;
    proc_row(lane, wv,
             p0, p1, p2, p3, p4, p5, p6, p7,
             p8, p9, p10, p11, p12, p13, p14, p15,
             Kb, qsf, ck, ci, wvi, eq_idx, i65_0, lam_0);

    // ---- f32 softmax + V gather + boundary blend (one row per wave) ----
    {
        const unsigned long long e = wvi[wv][lane];
        const float    sv = __uint_as_float((unsigned)(e >> 32));
        const unsigned vi = (unsigned)e;
        const float mx = dpp_wmax_f32(sv);
        const float p  = __expf(sv - mx);
        const float Z  = dpp_wsum_f32(p);
        const float w  = p / Z;
        // overwrite val slot with softmax weight (wave-local row, DS in-order)
        wvi[wv][lane] = ((unsigned long long)__float_as_uint(w) << 32)
                      | (unsigned long long)vi;

        float acc = 0.f;
#pragma unroll
        for (int j = 0; j < 64; ++j) {
            const unsigned long long ej = wvi[wv][j];   // broadcast, imm offset
            const float wj = __uint_as_float((unsigned)(ej >> 32));
            const unsigned ij = (unsigned)ej;
            acc = fmaf(wj, Vb[(ij << 6) + (unsigned)lane], acc);
        }
        {   // hedge: position 63 holds the rank-64 (threshold) element
            const unsigned long long e63 = wvi[wv][63];
            const float    wT  = __uint_as_float((unsigned)(e63 >> 32));
            const unsigned i64 = (unsigned)e63;
            acc += wT * lam_0 *
                   (Vb[((unsigned)i65_0 << 6) + (unsigned)lane]
                  - Vb[(i64 << 6) + (unsigned)lane]);
        }
        const int gq = qt * 16 + wv;
        outm[((size_t)bb * Nk + gq) * Ek + hh * DHk + lane] = acc;
    }
}

// ---------------------------------------------------------------------------
extern "C" void kernel_launch(void* const* d_in, const int* in_sizes, int n_in,
                              void* d_out, int out_size, void* d_ws, size_t ws_size,
                              hipStream_t stream)
{
    const float* query = (const float*)d_in[0];
    const float* key   = (const float*)d_in[1];
    const float* value = (const float*)d_in[2];
    const float* Wq    = (const float*)d_in[3];
    const float* bq    = (const float*)d_in[4];
    const float* Wk    = (const float*)d_in[5];
    const float* bk    = (const float*)d_in[6];
    const float* Wv    = (const float*)d_in[7];
    const float* bv    = (const float*)d_in[8];
    const float* Wo    = (const float*)d_in[9];
    const float* bo    = (const float*)d_in[10];
    float* out = (float*)d_out;
    (void)in_sizes; (void)n_in; (void)out_size; (void)ws_size;

    // 92 MB (ws >= 96 MB proven): qf|kf|v|attn f32 (16 MB ea) + kbf (8) +
    // xh|xl (8 ea, reused per GEMM) + wh|wl (2 ea, reused)
    const size_t seg  = (size_t)(Bk * Hk) * Nk * DHk;   // 4M elems
    const size_t wseg = (size_t)Ek * Ek;                 // 1M elems
    float* qfp = (float*)d_ws;
    float* kfp = qfp + seg;
    float* vws = kfp + seg;
    float* aws = vws + seg;
    unsigned short* kbf = (unsigned short*)(aws + seg);
    unsigned short* xh  = kbf + seg;
    unsigned short* xl  = xh + seg;
    unsigned short* wh  = xl + seg;
    unsigned short* wl  = wh + wseg;

    const dim3 blk(256);
    const dim3 gG(512);                    // gemm: 1D, XCD-swizzled inside
    const int  gX = (int)(seg  / 2048);    // cvt grid segments
    const int  gW = (int)(wseg / 2048);
    const dim3 gC(gX + gW);                // merged cvt grid

    // Q projection
    hipLaunchKernelGGL(cvt_split2, gC, blk, 0, stream, query, xh, xl, gX, Wq, wh, wl);
    hipLaunchKernelGGL((gemm_mfma<1>), gG, blk, 0, stream, xh, xl, wh, wl, bq, qfp, (unsigned short*)nullptr);
    // K projection (+ fused bf16 fragment-layout output for prefilter)
    hipLaunchKernelGGL(cvt_split2, gC, blk, 0, stream, key, xh, xl, gX, Wk, wh, wl);
    hipLaunchKernelGGL((gemm_mfma<1>), gG, blk, 0, stream, xh, xl, wh, wl, bk, kfp, kbf);
    // V projection
    hipLaunchKernelGGL(cvt_split2, gC, blk, 0, stream, value, xh, xl, gX, Wv, wh, wl);
    hipLaunchKernelGGL((gemm_mfma<1>), gG, blk, 0, stream, xh, xl, wh, wl, bv, vws, (unsigned short*)nullptr);
    // Attention
    hipLaunchKernelGGL(attn_topk_mfma, dim3(32 * 128), dim3(1024), 0, stream,
                       qfp, kfp, kbf, vws, aws);
    // Output projection
    hipLaunchKernelGGL(cvt_split2, gC, blk, 0, stream, aws, xh, xl, gX, Wo, wh, wl);
    hipLaunchKernelGGL((gemm_mfma<0>), gG, blk, 0, stream, xh, xl, wh, wl, bo, out, (unsigned short*)nullptr);
}

// Round 12
// 521.239 us; speedup vs baseline: 1.0975x; 1.0274x over previous
//
#include <hip/hip_runtime.h>
#include <stdint.h>
#include <math.h>

#define Bk 2
#define Nk 2048
#define Ek 1024
#define Hk 16
#define DHk 64
#define BLENDW 5e-5    // blend ramp width on scaled-score gap
#define PRECAND 96     // prefilter count target (>=65 + margin)
#define CANDCAP 128

using short8 = __attribute__((ext_vector_type(8))) short;
using f32x4  = __attribute__((ext_vector_type(4))) float;

__device__ __forceinline__ unsigned short bf16rne(float f) {
    const unsigned u = __float_as_uint(f);
    return (unsigned short)((u + 0x7FFFu + ((u >> 16) & 1u)) >> 16);
}

// 8 f32 -> 8 bf16-hi (ho) + 8 bf16-lo (lo), bit-identical to cvt_split.
__device__ __forceinline__ void cvt8hl(const float4 a, const float4 b,
                                       uint4& ho, uint4& lo) {
    const unsigned short h0 = bf16rne(a.x), h1 = bf16rne(a.y);
    const unsigned short h2 = bf16rne(a.z), h3 = bf16rne(a.w);
    const unsigned short h4 = bf16rne(b.x), h5 = bf16rne(b.y);
    const unsigned short h6 = bf16rne(b.z), h7 = bf16rne(b.w);
    const unsigned short l0 = bf16rne(a.x - __uint_as_float((unsigned)h0 << 16));
    const unsigned short l1 = bf16rne(a.y - __uint_as_float((unsigned)h1 << 16));
    const unsigned short l2 = bf16rne(a.z - __uint_as_float((unsigned)h2 << 16));
    const unsigned short l3 = bf16rne(a.w - __uint_as_float((unsigned)h3 << 16));
    const unsigned short l4 = bf16rne(b.x - __uint_as_float((unsigned)h4 << 16));
    const unsigned short l5 = bf16rne(b.y - __uint_as_float((unsigned)h5 << 16));
    const unsigned short l6 = bf16rne(b.z - __uint_as_float((unsigned)h6 << 16));
    const unsigned short l7 = bf16rne(b.w - __uint_as_float((unsigned)h7 << 16));
    ho.x = h0 | ((unsigned)h1 << 16); ho.y = h2 | ((unsigned)h3 << 16);
    ho.z = h4 | ((unsigned)h5 << 16); ho.w = h6 | ((unsigned)h7 << 16);
    lo.x = l0 | ((unsigned)l1 << 16); lo.y = l2 | ((unsigned)l3 << 16);
    lo.z = l4 | ((unsigned)l5 << 16); lo.w = l6 | ((unsigned)l7 << 16);
}

// ---------------------------------------------------------------------------
// cvt_w: all 4 weight matrices -> bf16 hi/lo pairs in ONE launch.
// grid 4*512; seg s handles W_s into whb/wlb + s*Ek*Ek.
// ---------------------------------------------------------------------------
__global__ __launch_bounds__(256) void cvt_w(
    const float* __restrict__ W0, const float* __restrict__ W1,
    const float* __restrict__ W2, const float* __restrict__ W3,
    unsigned short* __restrict__ whb, unsigned short* __restrict__ wlb)
{
    const int seg = blockIdx.x >> 9;       // 0..3
    const int loc = blockIdx.x & 511;
    const float* in = (seg == 0) ? W0 : (seg == 1) ? W1 : (seg == 2) ? W2 : W3;
    unsigned short* oh = whb + (size_t)seg * Ek * Ek;
    unsigned short* ol = wlb + (size_t)seg * Ek * Ek;
    const int i = loc * 256 + threadIdx.x;     // 8 elems/thread
    const float4 a = ((const float4*)in)[i * 2];
    const float4 c = ((const float4*)in)[i * 2 + 1];
    uint4 ho, lo;
    cvt8hl(a, c, ho, lo);
    ((uint4*)oh)[i] = ho;
    ((uint4*)ol)[i] = lo;
}

// ---------------------------------------------------------------------------
// Split-bf16 MFMA GEMM with INLINE X conversion (f32 -> hi/lo during staging;
// byte traffic identical to reading xh+xl, results bit-identical since same
// bf16rne).  C[m,c] = sum_k X[m,k]W[c,k] + bias[c] = Xh*Wh + Xh*Wl + Xl*Wh.
// Tile 128x64, K chunks of 32, 4 waves/block (proven r5/r11 config).
// MODE 1: fused Q/K/V, grid 1536 = 8 XCDs x 192 contiguous wids (12 panels);
//         proj = wid>>9 picks {X,W-pair,bias,out}; K also writes kbf in
//         FRAGMENT-CONTIGUOUS layout (verified r8).
// MODE 0: output projection, grid 512, X=aws, out[m*Ek+c].
// ---------------------------------------------------------------------------
template<int MODE>
__global__ __launch_bounds__(256, 4) void gemm_mfma(
    const float* __restrict__ X0, const float* __restrict__ X1,
    const float* __restrict__ X2,
    const unsigned short* __restrict__ whb, const unsigned short* __restrict__ wlb,
    const float* __restrict__ b0, const float* __restrict__ b1,
    const float* __restrict__ b2,
    float* __restrict__ o0, float* __restrict__ o1, float* __restrict__ o2,
    unsigned short* __restrict__ kbf)
{
    __shared__ unsigned short Ah[128][40], Al[128][40];   // [m][k] pad->80B rows
    __shared__ unsigned short Bh[64][40],  Bl[64][40];    // [c][k]

    const int tid  = threadIdx.x;
    const int lane = tid & 63;
    const int wv   = tid >> 6;
    const int n16  = lane & 15;
    const int quad = lane >> 4;

    // XCD-contiguous swizzle (bijective; grid%8==0 in both modes)
    int proj, loc;
    if (MODE == 1) {
        const int wid = (blockIdx.x & 7) * 192 + (blockIdx.x >> 3);  // 0..1535
        proj = wid >> 9;                   // 0..2
        loc  = wid & 511;
    } else {
        proj = 0;
        loc  = (blockIdx.x & 7) * 64 + (blockIdx.x >> 3);            // 0..511
    }
    const int mBase = (loc >> 4) * 128;
    const int nBase = (loc & 15) * 64;

    const float* X    = (proj == 0) ? X0 : (proj == 1) ? X1 : X2;
    const float* bias = (proj == 0) ? b0 : (proj == 1) ? b1 : b2;
    float*       out  = (proj == 0) ? o0 : (proj == 1) ? o1 : o2;
    unsigned short* obf = (MODE == 1 && proj == 1) ? kbf : (unsigned short*)nullptr;
    const unsigned short* Wh = whb + (size_t)proj * Ek * Ek;
    const unsigned short* Wl = wlb + (size_t)proj * Ek * Ek;

    f32x4 acc[2][4];
#pragma unroll
    for (int i = 0; i < 2; ++i)
#pragma unroll
        for (int j = 0; j < 4; ++j) acc[i][j] = (f32x4){0.f, 0.f, 0.f, 0.f};

    const int arow = tid >> 1, aoff = (tid & 1) * 16;   // A: 16 f32/thread
    const int brow = tid >> 2, boff = (tid & 3) * 8;    // B: 8 shorts/thread
    const size_t aIdx = (size_t)(mBase + arow) * Ek + aoff;
    const size_t bIdx = (size_t)(nBase + brow) * Ek + boff;

    for (int kt = 0; kt < Ek; kt += 32) {
        const float4 x0 = *(const float4*)(X + aIdx + kt);
        const float4 x1 = *(const float4*)(X + aIdx + kt + 4);
        const float4 x2 = *(const float4*)(X + aIdx + kt + 8);
        const float4 x3 = *(const float4*)(X + aIdx + kt + 12);
        const uint4 bh0 = *(const uint4*)(Wh + bIdx + kt);
        const uint4 bl0 = *(const uint4*)(Wl + bIdx + kt);
        uint4 ah0, al0, ah1, al1;
        cvt8hl(x0, x1, ah0, al0);
        cvt8hl(x2, x3, ah1, al1);
        __syncthreads();
        *(uint4*)&Ah[arow][aoff]     = ah0;
        *(uint4*)&Ah[arow][aoff + 8] = ah1;
        *(uint4*)&Al[arow][aoff]     = al0;
        *(uint4*)&Al[arow][aoff + 8] = al1;
        *(uint4*)&Bh[brow][boff]     = bh0;
        *(uint4*)&Bl[brow][boff]     = bl0;
        __syncthreads();

        const short8 fa_h0 = *(const short8*)&Ah[wv*32 +      n16][quad*8];
        const short8 fa_l0 = *(const short8*)&Al[wv*32 +      n16][quad*8];
        const short8 fa_h1 = *(const short8*)&Ah[wv*32 + 16 + n16][quad*8];
        const short8 fa_l1 = *(const short8*)&Al[wv*32 + 16 + n16][quad*8];
#pragma unroll
        for (int ct = 0; ct < 4; ++ct) {
            const short8 fb_h = *(const short8*)&Bh[ct*16 + n16][quad*8];
            const short8 fb_l = *(const short8*)&Bl[ct*16 + n16][quad*8];
            acc[0][ct] = __builtin_amdgcn_mfma_f32_16x16x32_bf16(fa_h0, fb_h, acc[0][ct], 0, 0, 0);
            acc[0][ct] = __builtin_amdgcn_mfma_f32_16x16x32_bf16(fa_h0, fb_l, acc[0][ct], 0, 0, 0);
            acc[0][ct] = __builtin_amdgcn_mfma_f32_16x16x32_bf16(fa_l0, fb_h, acc[0][ct], 0, 0, 0);
            acc[1][ct] = __builtin_amdgcn_mfma_f32_16x16x32_bf16(fa_h1, fb_h, acc[1][ct], 0, 0, 0);
            acc[1][ct] = __builtin_amdgcn_mfma_f32_16x16x32_bf16(fa_h1, fb_l, acc[1][ct], 0, 0, 0);
            acc[1][ct] = __builtin_amdgcn_mfma_f32_16x16x32_bf16(fa_l1, fb_h, acc[1][ct], 0, 0, 0);
        }
    }

    // epilogue: D row = quad*4+reg (within 16-tile), col = n16
#pragma unroll
    for (int mt = 0; mt < 2; ++mt)
#pragma unroll
    for (int ct = 0; ct < 4; ++ct) {
        const int c  = nBase + ct*16 + n16;
        const float bv = bias[c];
#pragma unroll
        for (int reg = 0; reg < 4; ++reg) {
            const int m = mBase + wv*32 + mt*16 + quad*4 + reg;
            const float o = acc[mt][ct][reg] + bv;
            if (MODE == 0) {
                out[(size_t)m * Ek + c] = o;
            } else {
                const int bb2 = m >> 11, nn = m & 2047;
                const int hh2 = c >> 6,  dd = c & 63;
                const size_t sb = (size_t)(bb2*Hk + hh2) * Nk * DHk;
                out[sb + (size_t)nn * DHk + dd] = o;
                if (obf) {
                    const size_t kdst = sb + (size_t)(nn >> 4) * 1024
                                      + ((dd >> 5) * 512)
                                      + ((((dd >> 3) & 3) * 16 + (nn & 15)) * 8)
                                      + (dd & 7);
                    obf[kdst] = bf16rne(o);
                }
            }
        }
    }
}

// ---------------------------------------------------------------------------
__device__ __forceinline__ unsigned fkey(float s) {
    const unsigned b = __float_as_uint(s);
    return (b & 0x80000000u) ? ~b : (b | 0x80000000u);
}
__device__ __forceinline__ unsigned long long dkey(double s) {
    unsigned long long b = (unsigned long long)__double_as_longlong(s);
    return (b & 0x8000000000000000ull) ? ~b : (b | 0x8000000000000000ull);
}
__device__ __forceinline__ double dinv(unsigned long long u) {
    const unsigned long long b =
        (u & 0x8000000000000000ull) ? (u & 0x7fffffffffffffffull) : ~u;
    return __longlong_as_double((long long)b);
}

// ---------------------------------------------------------------------------
// DPP wave-64 reductions / scan (rocPRIM & LLVM AtomicOptimizer patterns).
// ---------------------------------------------------------------------------
__device__ __forceinline__ int dpp_wsum_i32(int x) {
#define STEP(C) x += __builtin_amdgcn_update_dpp(0, x, C, 0xf, 0xf, true);
    STEP(0x111) STEP(0x112) STEP(0x114) STEP(0x118) STEP(0x142) STEP(0x143)
#undef STEP
    return __builtin_amdgcn_readlane(x, 63);
}
__device__ __forceinline__ float dpp_wsum_f32(float x) {
#define STEP(C) { const int t_ = __builtin_amdgcn_update_dpp(0, __float_as_int(x), C, 0xf, 0xf, true); \
                  x += __int_as_float(t_); }
    STEP(0x111) STEP(0x112) STEP(0x114) STEP(0x118) STEP(0x142) STEP(0x143)
#undef STEP
    return __int_as_float(__builtin_amdgcn_readlane(__float_as_int(x), 63));
}
__device__ __forceinline__ float dpp_wmax_f32(float x) {
#define STEP(C) { const int t_ = __builtin_amdgcn_update_dpp(__float_as_int(x), __float_as_int(x), C, 0xf, 0xf, false); \
                  x = fmaxf(x, __int_as_float(t_)); }
    STEP(0x111) STEP(0x112) STEP(0x114) STEP(0x118) STEP(0x142) STEP(0x143)
#undef STEP
    return __int_as_float(__builtin_amdgcn_readlane(__float_as_int(x), 63));
}
__device__ __forceinline__ unsigned dpp_wmin_u32(unsigned x) {
#define STEP(C) { const unsigned t_ = (unsigned)__builtin_amdgcn_update_dpp((int)x, (int)x, C, 0xf, 0xf, false); \
                  x = x < t_ ? x : t_; }
    STEP(0x111) STEP(0x112) STEP(0x114) STEP(0x118) STEP(0x142) STEP(0x143)
#undef STEP
    return (unsigned)__builtin_amdgcn_readlane((int)x, 63);
}
__device__ __forceinline__ unsigned dpp_wmax_u32(unsigned x) {
#define STEP(C) { const unsigned t_ = (unsigned)__builtin_amdgcn_update_dpp((int)x, (int)x, C, 0xf, 0xf, false); \
                  x = x > t_ ? x : t_; }
    STEP(0x111) STEP(0x112) STEP(0x114) STEP(0x118) STEP(0x142) STEP(0x143)
#undef STEP
    return (unsigned)__builtin_amdgcn_readlane((int)x, 63);
}
// inclusive prefix-sum across 64 lanes (LLVM buildScan pattern)
__device__ __forceinline__ int dpp_wprefix_incl_i32(int x) {
    x += __builtin_amdgcn_update_dpp(0, x, 0x111, 0xf, 0xf, true);  // row_shr:1
    x += __builtin_amdgcn_update_dpp(0, x, 0x112, 0xf, 0xf, true);  // row_shr:2
    x += __builtin_amdgcn_update_dpp(0, x, 0x114, 0xf, 0xf, true);  // row_shr:4
    x += __builtin_amdgcn_update_dpp(0, x, 0x118, 0xf, 0xf, true);  // row_shr:8
    x += __builtin_amdgcn_update_dpp(0, x, 0x142, 0xa, 0xf, true);  // bcast15 -> rows 1,3
    x += __builtin_amdgcn_update_dpp(0, x, 0x143, 0xc, 0xf, true);  // bcast31 -> rows 2,3
    return x;
}

// ---------------------------------------------------------------------------
// Per-row top-k: prefilter -> f64 recheck -> exact top-64 + rank-65 blend.
// (unchanged - proven 293 us)
// ---------------------------------------------------------------------------
__device__ __forceinline__ void proc_row(
    const int lane, const int lrow,
    unsigned s0, unsigned s1, unsigned s2, unsigned s3,
    unsigned s4, unsigned s5, unsigned s6, unsigned s7,
    unsigned s8, unsigned s9, unsigned s10, unsigned s11,
    unsigned s12, unsigned s13, unsigned s14, unsigned s15,
    const float* __restrict__ Kb, const float (*qsf)[68],
    unsigned long long (*ck)[CANDCAP], unsigned (*ci)[CANDCAP],
    unsigned long long (*wvi)[64], unsigned (*eq_idx)[64],
    int& i65_out, float& lam_out)
{
    const unsigned long long lmask = (1ull << lane) - 1ull;

    // shifted copies: q_w = lo-half in compare space (hi-half compares use s_w)
    const unsigned q0 = s0 << 16,  q1 = s1 << 16,  q2 = s2 << 16,  q3 = s3 << 16;
    const unsigned q4 = s4 << 16,  q5 = s5 << 16,  q6 = s6 << 16,  q7 = s7 << 16;
    const unsigned q8 = s8 << 16,  q9 = s9 << 16,  q10 = s10 << 16, q11 = s11 << 16;
    const unsigned q12 = s12 << 16, q13 = s13 << 16, q14 = s14 << 16, q15 = s15 << 16;

    // A) bracket: per-lane top-2 over the 32 junk-space values.
    unsigned m1 = 0u, m2 = 0u;
#define T2(V) { const unsigned t_ = (V) < m1 ? (V) : m1; \
                m1 = m1 > (V) ? m1 : (V);  m2 = m2 > t_ ? m2 : t_; }
    T2(s0)  T2(s1)  T2(s2)  T2(s3)  T2(s4)  T2(s5)  T2(s6)  T2(s7)
    T2(s8)  T2(s9)  T2(s10) T2(s11) T2(s12) T2(s13) T2(s14) T2(s15)
    T2(q0)  T2(q1)  T2(q2)  T2(q3)  T2(q4)  T2(q5)  T2(q6)  T2(q7)
    T2(q8)  T2(q9)  T2(q10) T2(q11) T2(q12) T2(q13) T2(q14) T2(q15)
#undef T2
    unsigned lo16 = dpp_wmin_u32(m2) >> 16;   // count(>=lo16) >= 2/lane -> >=128
    unsigned hi16 = dpp_wmax_u32(m1) >> 16;   // count(>=hi16+1) == 0

    // binary search: largest TH with count >= PRECAND; window-accept [96,128]
    while (lo16 < hi16) {
        const unsigned mid = lo16 + ((hi16 - lo16) >> 1) + 1u;
        const unsigned M = mid << 16;
        int c0 = 0, c1 = 0, c2 = 0, c3 = 0;    // 4 accums: break dep chain
        c0 += (s0  >= M); c0 += (q0  >= M); c0 += (s1  >= M); c0 += (q1  >= M);
        c0 += (s2  >= M); c0 += (q2  >= M); c0 += (s3  >= M); c0 += (q3  >= M);
        c1 += (s4  >= M); c1 += (q4  >= M); c1 += (s5  >= M); c1 += (q5  >= M);
        c1 += (s6  >= M); c1 += (q6  >= M); c1 += (s7  >= M); c1 += (q7  >= M);
        c2 += (s8  >= M); c2 += (q8  >= M); c2 += (s9  >= M); c2 += (q9  >= M);
        c2 += (s10 >= M); c2 += (q10 >= M); c2 += (s11 >= M); c2 += (q11 >= M);
        c3 += (s12 >= M); c3 += (q12 >= M); c3 += (s13 >= M); c3 += (q13 >= M);
        c3 += (s14 >= M); c3 += (q14 >= M); c3 += (s15 >= M); c3 += (q15 >= M);
        const int c = dpp_wsum_i32((c0 + c1) + (c2 + c3));
        if (c >= PRECAND) {
            lo16 = mid;
            if (c <= CANDCAP) break;       // window accept (superset-safe)
        } else hi16 = mid - 1u;
    }
    const unsigned THsh = lo16 << 16;

    // collect candidates, LANE-MAJOR: per-lane count -> DPP prefix -> scatter
    int cnt = 0;
#define CC(S, Q) { cnt += ((Q) >= THsh); cnt += ((S) >= THsh); }
    CC(s0, q0)    CC(s1, q1)    CC(s2, q2)    CC(s3, q3)
    CC(s4, q4)    CC(s5, q5)    CC(s6, q6)    CC(s7, q7)
    CC(s8, q8)    CC(s9, q9)    CC(s10, q10)  CC(s11, q11)
    CC(s12, q12)  CC(s13, q13)  CC(s14, q14)  CC(s15, q15)
#undef CC
    const int incl = dpp_wprefix_incl_i32(cnt);
    int pos = incl - cnt;                       // exclusive prefix
    int nc = __builtin_amdgcn_readlane(incl, 63);
    if (nc > CANDCAP) nc = CANDCAP;
#define CE(W, S, Q) { \
        if ((Q) >= THsh) { \
            if (pos < CANDCAP) \
                ci[lrow][pos] = (unsigned)((((W) >> 2) * 512) + (((W) & 3) * 128) + 2 * lane); \
            ++pos; } \
        if ((S) >= THsh) { \
            if (pos < CANDCAP) \
                ci[lrow][pos] = (unsigned)((((W) >> 2) * 512) + (((W) & 3) * 128) + 2 * lane + 1); \
            ++pos; } }
    CE(0, s0, q0)     CE(1, s1, q1)     CE(2, s2, q2)     CE(3, s3, q3)
    CE(4, s4, q4)     CE(5, s5, q5)     CE(6, s6, q6)     CE(7, s7, q7)
    CE(8, s8, q8)     CE(9, s9, q9)     CE(10, s10, q10)  CE(11, s11, q11)
    CE(12, s12, q12)  CE(13, s13, q13)  CE(14, s14, q14)  CE(15, s15, q15)
#undef CE

    // B) f64 rescore from f32 q,k: lane = (c8, d8); 8 cands per batch
    const int c8 = lane >> 3, d8 = lane & 7;
    const float* qrow = &qsf[lrow][d8 * 8];
    const double qd0 = (double)qrow[0], qd1 = (double)qrow[1];
    const double qd2 = (double)qrow[2], qd3 = (double)qrow[3];
    const double qd4 = (double)qrow[4], qd5 = (double)qrow[5];
    const double qd6 = (double)qrow[6], qd7 = (double)qrow[7];
    const int nb = (nc + 7) >> 3;
    for (int b = 0; b < nb; ++b) {
        const int s  = b * 8 + c8;
        const int s2 = s < nc ? s : nc - 1;
        const unsigned cidx = ci[lrow][s2];
        const unsigned kb32 = (cidx << 6) + (unsigned)(d8 * 8);
        const float2 kv0 = *(const float2*)(Kb + kb32);
        const float2 kv1 = *(const float2*)(Kb + kb32 + 2);
        const float2 kv2 = *(const float2*)(Kb + kb32 + 4);
        const float2 kv3 = *(const float2*)(Kb + kb32 + 6);
        double acc = 0.0;
        acc = fma(qd0, (double)kv0.x, acc);
        acc = fma(qd1, (double)kv0.y, acc);
        acc = fma(qd2, (double)kv1.x, acc);
        acc = fma(qd3, (double)kv1.y, acc);
        acc = fma(qd4, (double)kv2.x, acc);
        acc = fma(qd5, (double)kv2.y, acc);
        acc = fma(qd6, (double)kv3.x, acc);
        acc = fma(qd7, (double)kv3.y, acc);
        acc += __shfl_xor(acc, 1);
        acc += __shfl_xor(acc, 2);
        acc += __shfl_xor(acc, 4);
        if (d8 == 0 && s < nc) ck[lrow][s] = dkey(acc * 0.125);
    }

    // C) exact top-64 among candidates (64-bit keys, <=2 per lane)
    const unsigned long long k0 = (lane      < nc) ? ck[lrow][lane]      : 0ull;
    const unsigned long long k1 = (lane + 64 < nc) ? ck[lrow][lane + 64] : 0ull;
    const unsigned idx0 = ci[lrow][lane];
    const unsigned idx1 = ci[lrow][(lane + 64) & (CANDCAP - 1)];
    const unsigned kh0 = (unsigned)(k0 >> 32), kh1 = (unsigned)(k1 >> 32);
    const unsigned kl0 = (unsigned)k0,         kl1 = (unsigned)k1;

    // stage 1: H = hi32 of 64th-largest key
    unsigned H;
    {
        const unsigned i0 = (k0 != 0ull) ? kh0 : 0xFFFFFFFFu;
        const unsigned i1 = (k1 != 0ull) ? kh1 : 0xFFFFFFFFu;
        unsigned lo = dpp_wmin_u32(i0 < i1 ? i0 : i1);
        unsigned hi = dpp_wmax_u32(kh0 > kh1 ? kh0 : kh1);
        bool done = false;
        while (lo < hi) {
            const unsigned mid = lo + ((hi - lo) >> 1) + 1u;
            const int c = __popcll(__ballot(kh0 >= mid))
                        + __popcll(__ballot(kh1 >= mid));
            if (c == 64) {
                const unsigned v0 = (kh0 >= mid) ? kh0 : 0xFFFFFFFFu;
                const unsigned v1m = (kh1 >= mid) ? kh1 : 0xFFFFFFFFu;
                H = dpp_wmin_u32(v0 < v1m ? v0 : v1m);
                done = true; break;
            }
            if (c >= 64) lo = mid; else hi = mid - 1u;
        }
        if (!done) H = lo;
    }
    const int cGtHi = __popcll(__ballot(kh0 > H))
                    + __popcll(__ballot(kh1 > H));
    const int need1 = 64 - cGtHi;

    // stage 2: Tlo = lo32 of 64th key (need1-th largest lo32 among hi==H)
    const bool e0v = (kh0 == H) && (k0 != 0ull);
    const bool e1v = (kh1 == H) && (k1 != 0ull);
    const int cEq = __popcll(__ballot(e0v)) + __popcll(__ballot(e1v));
    unsigned Tlo;
    if (need1 == cEq) {                // all ties included -> min lo32
        const unsigned v0 = e0v ? kl0 : 0xFFFFFFFFu;
        const unsigned v1m = e1v ? kl1 : 0xFFFFFFFFu;
        Tlo = dpp_wmin_u32(v0 < v1m ? v0 : v1m);
    } else if (need1 == 1) {           // single needed -> max lo32
        const unsigned v0 = e0v ? kl0 : 0u;
        const unsigned v1m = e1v ? kl1 : 0u;
        Tlo = dpp_wmax_u32(v0 > v1m ? v0 : v1m);
    } else {
        unsigned lo = 0u, hi = 0xFFFFFFFFu;
        bool done = false;
        while (lo < hi) {
            const unsigned mid = lo + ((hi - lo) >> 1) + 1u;
            const int c = __popcll(__ballot(e0v && kl0 >= mid))
                        + __popcll(__ballot(e1v && kl1 >= mid));
            if (c == need1) {
                const unsigned v0 = (e0v && kl0 >= mid) ? kl0 : 0xFFFFFFFFu;
                const unsigned v1m = (e1v && kl1 >= mid) ? kl1 : 0xFFFFFFFFu;
                Tlo = dpp_wmin_u32(v0 < v1m ? v0 : v1m);
                done = true; break;
            }
            if (c >= need1) lo = mid; else hi = mid - 1u;
        }
        if (!done) Tlo = lo;
    }
    const unsigned long long T = ((unsigned long long)H << 32) | Tlo;

    int base = 0;                      // emit k > T as packed (f32 val, idx)
    {
        const bool g0 = k0 > T;
        unsigned long long m = __ballot(g0);
        if (g0) {
            const int pos2 = base + __popcll(m & lmask);
            wvi[lrow][pos2] = ((unsigned long long)__float_as_uint((float)dinv(k0)) << 32)
                            | (unsigned long long)idx0;
        }
        base += __popcll(m);
        const bool g1 = k1 > T;
        m = __ballot(g1);
        if (g1) {
            const int pos2 = base + __popcll(m & lmask);
            wvi[lrow][pos2] = ((unsigned long long)__float_as_uint((float)dinv(k1)) << 32)
                            | (unsigned long long)idx1;
        }
        base += __popcll(m);
    }

    int ne = 0;                        // ties k == T
    {
        const bool e0 = k0 == T;
        unsigned long long m = __ballot(e0);
        if (e0) {
            const int pos2 = ne + __popcll(m & lmask);
            if (pos2 < 64) eq_idx[lrow][pos2] = idx0;
        }
        ne += __popcll(m);
        const bool e1 = k1 == T;
        m = __ballot(e1);
        if (e1) {
            const int pos2 = ne + __popcll(m & lmask);
            if (pos2 < 64) eq_idx[lrow][pos2] = idx1;
        }
        ne += __popcll(m);
    }
    if (ne > 64) ne = 64;

    const int   need = 64 - base;
    const float tvf  = (float)dinv(T);
    if (lane < need) {                 // ties: ascending index (jax rule)
        unsigned my = 0u;
        for (int j = 0; j < ne; ++j) {
            const unsigned v = eq_idx[lrow][j];
            int rank = 0;
            for (int j2 = 0; j2 < ne; ++j2) rank += (eq_idx[lrow][j2] < v) ? 1 : 0;
            if (rank == lane) my = v;
        }
        wvi[lrow][base + lane] = ((unsigned long long)__float_as_uint(tvf) << 32)
                               | (unsigned long long)my;
    }

    // 65th element (max key < T) via 2-stage DPP max (register-only)
    const unsigned mh0 = (k0 < T) ? kh0 : 0u;
    const unsigned mh1 = (k1 < T) ? kh1 : 0u;     // invalid k=0 -> contributes 0
    const unsigned Hm = dpp_wmax_u32(mh0 > mh1 ? mh0 : mh1);
    const unsigned ml0 = (k0 < T && kh0 == Hm) ? kl0 : 0u;
    const unsigned ml1 = (k1 < T && kh1 == Hm) ? kl1 : 0u;
    const unsigned Lm = dpp_wmax_u32(ml0 > ml1 ? ml0 : ml1);
    const unsigned long long m2k = ((unsigned long long)Hm << 32) | Lm;

    int i65 = 0;
    {
        unsigned long long mm = __ballot(k0 == m2k && m2k != 0ull);
        if (mm) i65 = __shfl((int)idx0, (int)(__ffsll((long long)mm) - 1));
        else {
            mm = __ballot(k1 == m2k && m2k != 0ull);
            if (mm) i65 = __shfl((int)idx1, (int)(__ffsll((long long)mm) - 1));
        }
    }
    double fr = (dinv(T) - dinv(m2k)) * (1.0 / BLENDW);
    if (fr > 1.0) fr = 1.0;
    i65_out = i65;
    lam_out = (m2k == 0ull) ? 0.f : (float)(0.5 * (1.0 - fr));
}

// ---------------------------------------------------------------------------
// MFMA-prefiltered attn (unchanged - proven 293 us): bf16 MFMA scores ->
// prefilter -> f64 recheck -> exact top-64 + rank-65 blend -> softmax + V.
// 1024 thr = 16 waves, one q-row per wave; keys in named scalars (no scratch).
// ---------------------------------------------------------------------------
__global__ __launch_bounds__(1024, 8) void attn_topk_mfma(
    const float* __restrict__ qf, const float* __restrict__ kf,
    const unsigned short* __restrict__ kbf,
    const float* __restrict__ vh, float* __restrict__ outm)
{
    // sc (16x516 f32 = 33024 B) aliased with ck (16x128 u64) + ci (16x128 u32)
    __shared__ __align__(16) char uS[33024];
    float (*sc)[516] = (float(*)[516])uS;
    unsigned long long (*ck)[CANDCAP] = (unsigned long long(*)[CANDCAP])uS;
    unsigned (*ci)[CANDCAP] = (unsigned(*)[CANDCAP])(uS + 16384);

    __shared__ float          qsf[16][68];         // f32 q rows (exact)
    __shared__ unsigned short qbf[16][72];         // bf16 q rows
    __shared__ unsigned long long wvi[16][64];     // packed (val|w, idx)
    __shared__ unsigned eq_idx[16][64];

    const int tid  = threadIdx.x;
    const int lane = tid & 63;
    const int wv   = tid >> 6;             // 0..15; wave wv owns q-row wv

    // XCD-aware bijective swizzle (grid 4096 = 8 XCDs x 512, 4096%8==0):
    // all 128 q-tiles of a slot on one XCD -> K/V stay L2-resident.
    const int wid  = (blockIdx.x & 7) * 512 + (blockIdx.x >> 3);
    const int slot = wid >> 7;             // 0..31 head slot
    const int qt   = wid & 127;
    const int bb   = slot >> 4;
    const int hh   = slot & 15;

    const float*          Qb = qf  + (size_t)slot * Nk * DHk + (size_t)qt * 16 * DHk;
    const float*          Kb = kf  + (size_t)slot * Nk * DHk;
    const unsigned short* KB = kbf + (size_t)slot * Nk * DHk;
    const float*          Vb = vh  + (size_t)slot * Nk * DHk;

    {   // stage 16 q rows: f32 + bf16 copies (1024 thr: 1 elem each)
        const int r = tid >> 6, d = tid & 63;
        const float qv = Qb[r * DHk + d];
        qsf[r][d] = qv;
        qbf[r][d] = bf16rne(qv);
    }
    __syncthreads();

    // A-fragments: A[m=lane&15][k=quad*8+j]
    const int n16  = lane & 15;
    const int quad = lane >> 4;
    short8 afrag0, afrag1;
    afrag0 = *(const short8*)&qbf[n16][quad * 8];
    afrag1 = *(const short8*)&qbf[n16][32 + quad * 8];

    // Packed hi-16 prefilter keys: 16 NAMED u32 words. Word w holds logical
    // keys {2w (lo), 2w+1 (hi)}; col(2w)=(w>>2)*512+(w&3)*128+2*lane, +1 odd.
    unsigned p0, p1, p2, p3, p4, p5, p6, p7;
    unsigned p8, p9, p10, p11, p12, p13, p14, p15;
    const int rowD = quad * 4;

    // ---- phase 1: bf16 MFMA scores, 4 chunks x 512 cols (manual unroll) ----
    // 16 waves x 2 MFMA-tiles per chunk cover the 32 ctiles. kbf is in
    // fragment-contiguous layout: tile t -> 1KB lane-linear block per half.
#define QK_TILE(CH, T, ACC) { \
    const unsigned short* kp = KB + (((CH) * 32) + (wv * 2 + (T))) * 1024 + lane * 8; \
    const short8 b0_ = *(const short8*)(kp); \
    const short8 b1_ = *(const short8*)(kp + 512); \
    ACC = __builtin_amdgcn_mfma_f32_16x16x32_bf16(afrag0, b0_, ACC, 0, 0, 0); \
    ACC = __builtin_amdgcn_mfma_f32_16x16x32_bf16(afrag1, b1_, ACC, 0, 0, 0); \
}
#define SC_STORE(T, ACC) { \
    const int ccol = (wv * 2 + (T)) * 16 + n16; \
    sc[rowD + 0][ccol] = ACC[0]; sc[rowD + 1][ccol] = ACC[1]; \
    sc[rowD + 2][ccol] = ACC[2]; sc[rowD + 3][ccol] = ACC[3]; \
}
#define PACKW(J, DEST) { \
    const float2 pr_ = *(const float2*)&sc[wv][(J) * 128 + 2 * lane]; \
    DEST = (fkey(pr_.x) >> 16) | ((fkey(pr_.y) >> 16) << 16); \
}
#define DO_CHUNK(CH, D0, D1, D2, D3) { \
    f32x4 ac0 = {0.f,0.f,0.f,0.f}, ac1 = {0.f,0.f,0.f,0.f}; \
    QK_TILE(CH, 0, ac0) QK_TILE(CH, 1, ac1) \
    __syncthreads();                   /* prev chunk's sc reads done */ \
    SC_STORE(0, ac0) SC_STORE(1, ac1) \
    __syncthreads(); \
    PACKW(0, D0) PACKW(1, D1) PACKW(2, D2) PACKW(3, D3) \
}
    DO_CHUNK(0, p0,  p1,  p2,  p3)
    DO_CHUNK(1, p4,  p5,  p6,  p7)
    DO_CHUNK(2, p8,  p9,  p10, p11)
    DO_CHUNK(3, p12, p13, p14, p15)
#undef DO_CHUNK
#undef PACKW
#undef SC_STORE
#undef QK_TILE

    __syncthreads();                       // sc dead; ck/ci alias safe

    // ---- per-row: prefilter -> f64 recheck -> exact top-64 + 65th ----
    int i65_0; float lam_0;
    proc_row(lane, wv,
             p0, p1, p2, p3, p4, p5, p6, p7,
             p8, p9, p10, p11, p12, p13, p14, p15,
             Kb, qsf, ck, ci, wvi, eq_idx, i65_0, lam_0);

    // ---- f32 softmax + V gather + boundary blend (one row per wave) ----
    {
        const unsigned long long e = wvi[wv][lane];
        const float    sv = __uint_as_float((unsigned)(e >> 32));
        const unsigned vi = (unsigned)e;
        const float mx = dpp_wmax_f32(sv);
        const float p  = __expf(sv - mx);
        const float Z  = dpp_wsum_f32(p);
        const float w  = p / Z;
        // overwrite val slot with softmax weight (wave-local row, DS in-order)
        wvi[wv][lane] = ((unsigned long long)__float_as_uint(w) << 32)
                      | (unsigned long long)vi;

        float acc = 0.f;
#pragma unroll
        for (int j = 0; j < 64; ++j) {
            const unsigned long long ej = wvi[wv][j];   // broadcast, imm offset
            const float wj = __uint_as_float((unsigned)(ej >> 32));
            const unsigned ij = (unsigned)ej;
            acc = fmaf(wj, Vb[(ij << 6) + (unsigned)lane], acc);
        }
        {   // hedge: position 63 holds the rank-64 (threshold) element
            const unsigned long long e63 = wvi[wv][63];
            const float    wT  = __uint_as_float((unsigned)(e63 >> 32));
            const unsigned i64 = (unsigned)e63;
            acc += wT * lam_0 *
                   (Vb[((unsigned)i65_0 << 6) + (unsigned)lane]
                  - Vb[(i64 << 6) + (unsigned)lane]);
        }
        const int gq = qt * 16 + wv;
        outm[((size_t)bb * Nk + gq) * Ek + hh * DHk + lane] = acc;
    }
}

// ---------------------------------------------------------------------------
extern "C" void kernel_launch(void* const* d_in, const int* in_sizes, int n_in,
                              void* d_out, int out_size, void* d_ws, size_t ws_size,
                              hipStream_t stream)
{
    const float* query = (const float*)d_in[0];
    const float* key   = (const float*)d_in[1];
    const float* value = (const float*)d_in[2];
    const float* Wq    = (const float*)d_in[3];
    const float* bq    = (const float*)d_in[4];
    const float* Wk    = (const float*)d_in[5];
    const float* bk    = (const float*)d_in[6];
    const float* Wv    = (const float*)d_in[7];
    const float* bv    = (const float*)d_in[8];
    const float* Wo    = (const float*)d_in[9];
    const float* bo    = (const float*)d_in[10];
    float* out = (float*)d_out;
    (void)in_sizes; (void)n_in; (void)out_size; (void)ws_size;

    // 88 MB: qf|kf|v|attn f32 (16 MB ea) + kbf (8) + whb|wlb (8 ea, 4 W's)
    const size_t seg  = (size_t)(Bk * Hk) * Nk * DHk;   // 4M elems
    const size_t wseg = (size_t)Ek * Ek;                 // 1M elems
    float* qfp = (float*)d_ws;
    float* kfp = qfp + seg;
    float* vws = kfp + seg;
    float* aws = vws + seg;
    unsigned short* kbf = (unsigned short*)(aws + seg);
    unsigned short* whb = kbf + seg;                     // 4 x wseg
    unsigned short* wlb = whb + 4 * wseg;                // 4 x wseg

    const dim3 blk(256);

    // 1) all 4 weight matrices -> bf16 hi/lo (one launch, 2048 blocks)
    hipLaunchKernelGGL(cvt_w, dim3(4 * 512), blk, 0, stream,
                       Wq, Wk, Wv, Wo, whb, wlb);
    // 2) fused Q/K/V projections (inline X conversion; K writes kbf)
    hipLaunchKernelGGL((gemm_mfma<1>), dim3(3 * 512), blk, 0, stream,
                       query, key, value, whb, wlb, bq, bk, bv,
                       qfp, kfp, vws, kbf);
    // 3) attention
    hipLaunchKernelGGL(attn_topk_mfma, dim3(32 * 128), dim3(1024), 0, stream,
                       qfp, kfp, kbf, vws, aws);
    // 4) output projection (inline X conversion; W = slot 3)
    hipLaunchKernelGGL((gemm_mfma<0>), dim3(512), blk, 0, stream,
                       aws, (const float*)nullptr, (const float*)nullptr,
                       whb + 3 * wseg, wlb + 3 * wseg,
                       bo, (const float*)nullptr, (const float*)nullptr,
                       out, (float*)nullptr, (float*)nullptr,
                       (unsigned short*)nullptr);
}

// Round 13
// 519.525 us; speedup vs baseline: 1.1011x; 1.0033x over previous
//
#include <hip/hip_runtime.h>
#include <stdint.h>
#include <math.h>

#define Bk 2
#define Nk 2048
#define Ek 1024
#define Hk 16
#define DHk 64
#define BLENDW 5e-5    // blend ramp width on scaled-score gap
#define PRECAND 96     // prefilter count target (>=65 + margin)
#define CANDCAP 128

using short8 = __attribute__((ext_vector_type(8))) short;
using f32x4  = __attribute__((ext_vector_type(4))) float;

__device__ __forceinline__ unsigned short bf16rne(float f) {
    const unsigned u = __float_as_uint(f);
    return (unsigned short)((u + 0x7FFFu + ((u >> 16) & 1u)) >> 16);
}

// 8 f32 -> 8 bf16-hi (ho) + 8 bf16-lo (lo), bit-identical to cvt_split.
__device__ __forceinline__ void cvt8hl(const float4 a, const float4 b,
                                       uint4& ho, uint4& lo) {
    const unsigned short h0 = bf16rne(a.x), h1 = bf16rne(a.y);
    const unsigned short h2 = bf16rne(a.z), h3 = bf16rne(a.w);
    const unsigned short h4 = bf16rne(b.x), h5 = bf16rne(b.y);
    const unsigned short h6 = bf16rne(b.z), h7 = bf16rne(b.w);
    const unsigned short l0 = bf16rne(a.x - __uint_as_float((unsigned)h0 << 16));
    const unsigned short l1 = bf16rne(a.y - __uint_as_float((unsigned)h1 << 16));
    const unsigned short l2 = bf16rne(a.z - __uint_as_float((unsigned)h2 << 16));
    const unsigned short l3 = bf16rne(a.w - __uint_as_float((unsigned)h3 << 16));
    const unsigned short l4 = bf16rne(b.x - __uint_as_float((unsigned)h4 << 16));
    const unsigned short l5 = bf16rne(b.y - __uint_as_float((unsigned)h5 << 16));
    const unsigned short l6 = bf16rne(b.z - __uint_as_float((unsigned)h6 << 16));
    const unsigned short l7 = bf16rne(b.w - __uint_as_float((unsigned)h7 << 16));
    ho.x = h0 | ((unsigned)h1 << 16); ho.y = h2 | ((unsigned)h3 << 16);
    ho.z = h4 | ((unsigned)h5 << 16); ho.w = h6 | ((unsigned)h7 << 16);
    lo.x = l0 | ((unsigned)l1 << 16); lo.y = l2 | ((unsigned)l3 << 16);
    lo.z = l4 | ((unsigned)l5 << 16); lo.w = l6 | ((unsigned)l7 << 16);
}

// ---------------------------------------------------------------------------
// cvt_w: all 4 weight matrices -> bf16 hi/lo pairs in ONE launch.
// ---------------------------------------------------------------------------
__global__ __launch_bounds__(256) void cvt_w(
    const float* __restrict__ W0, const float* __restrict__ W1,
    const float* __restrict__ W2, const float* __restrict__ W3,
    unsigned short* __restrict__ whb, unsigned short* __restrict__ wlb)
{
    const int seg = blockIdx.x >> 9;       // 0..3
    const int loc = blockIdx.x & 511;
    const float* in = (seg == 0) ? W0 : (seg == 1) ? W1 : (seg == 2) ? W2 : W3;
    unsigned short* oh = whb + (size_t)seg * Ek * Ek;
    unsigned short* ol = wlb + (size_t)seg * Ek * Ek;
    const int i = loc * 256 + threadIdx.x;     // 8 elems/thread
    const float4 a = ((const float4*)in)[i * 2];
    const float4 c = ((const float4*)in)[i * 2 + 1];
    uint4 ho, lo;
    cvt8hl(a, c, ho, lo);
    ((uint4*)oh)[i] = ho;
    ((uint4*)ol)[i] = lo;
}

// ---------------------------------------------------------------------------
// Split-bf16 MFMA GEMM with INLINE X conversion + 1-DEEP REGISTER PREFETCH
// (v15): tile k+1's global loads issue BEFORE tile k's MFMA section, so HBM
// latency hides under the 36 MFMAs. Compiler can't hoist loads across
// __syncthreads(), so the old loop serialized latency every k-step.
// Results bit-identical (same loads, same cvt, same MFMA order).
// Tile 128x64, K chunks of 32, 4 waves/block, XCD-contiguous grid swizzle.
// MODE 1: fused Q/K/V (grid 1536); K also writes kbf in FRAGMENT-CONTIGUOUS
// layout (verified r8). MODE 0: output projection (grid 512).
// ---------------------------------------------------------------------------
template<int MODE>
__global__ __launch_bounds__(256, 4) void gemm_mfma(
    const float* __restrict__ X0, const float* __restrict__ X1,
    const float* __restrict__ X2,
    const unsigned short* __restrict__ whb, const unsigned short* __restrict__ wlb,
    const float* __restrict__ b0, const float* __restrict__ b1,
    const float* __restrict__ b2,
    float* __restrict__ o0, float* __restrict__ o1, float* __restrict__ o2,
    unsigned short* __restrict__ kbf)
{
    __shared__ unsigned short Ah[128][40], Al[128][40];   // [m][k] pad->80B rows
    __shared__ unsigned short Bh[64][40],  Bl[64][40];    // [c][k]

    const int tid  = threadIdx.x;
    const int lane = tid & 63;
    const int wv   = tid >> 6;
    const int n16  = lane & 15;
    const int quad = lane >> 4;

    // XCD-contiguous swizzle (bijective; grid%8==0 in both modes)
    int proj, loc;
    if (MODE == 1) {
        const int wid = (blockIdx.x & 7) * 192 + (blockIdx.x >> 3);  // 0..1535
        proj = wid >> 9;                   // 0..2
        loc  = wid & 511;
    } else {
        proj = 0;
        loc  = (blockIdx.x & 7) * 64 + (blockIdx.x >> 3);            // 0..511
    }
    const int mBase = (loc >> 4) * 128;
    const int nBase = (loc & 15) * 64;

    const float* X    = (proj == 0) ? X0 : (proj == 1) ? X1 : X2;
    const float* bias = (proj == 0) ? b0 : (proj == 1) ? b1 : b2;
    float*       out  = (proj == 0) ? o0 : (proj == 1) ? o1 : o2;
    unsigned short* obf = (MODE == 1 && proj == 1) ? kbf : (unsigned short*)nullptr;
    const unsigned short* Wh = whb + (size_t)proj * Ek * Ek;
    const unsigned short* Wl = wlb + (size_t)proj * Ek * Ek;

    f32x4 acc[2][4];
#pragma unroll
    for (int i = 0; i < 2; ++i)
#pragma unroll
        for (int j = 0; j < 4; ++j) acc[i][j] = (f32x4){0.f, 0.f, 0.f, 0.f};

    const int arow = tid >> 1, aoff = (tid & 1) * 16;   // A: 16 f32/thread
    const int brow = tid >> 2, boff = (tid & 3) * 8;    // B: 8 shorts/thread
    const size_t aIdx = (size_t)(mBase + arow) * Ek + aoff;
    const size_t bIdx = (size_t)(nBase + brow) * Ek + boff;

    // prologue: prefetch tile 0
    float4 x0 = *(const float4*)(X + aIdx);
    float4 x1 = *(const float4*)(X + aIdx + 4);
    float4 x2 = *(const float4*)(X + aIdx + 8);
    float4 x3 = *(const float4*)(X + aIdx + 12);
    uint4  wb = *(const uint4*)(Wh + bIdx);
    uint4  wl = *(const uint4*)(Wl + bIdx);

    for (int kt = 0; kt < Ek; kt += 32) {
        uint4 ah0, al0, ah1, al1;
        cvt8hl(x0, x1, ah0, al0);
        cvt8hl(x2, x3, ah1, al1);
        const uint4 bh0 = wb, bl0 = wl;
        __syncthreads();
        *(uint4*)&Ah[arow][aoff]     = ah0;
        *(uint4*)&Ah[arow][aoff + 8] = ah1;
        *(uint4*)&Al[arow][aoff]     = al0;
        *(uint4*)&Al[arow][aoff + 8] = al1;
        *(uint4*)&Bh[brow][boff]     = bh0;
        *(uint4*)&Bl[brow][boff]     = bl0;
        __syncthreads();

        // issue NEXT tile's global loads before the MFMA section: their
        // latency hides under ds_read + 36 MFMAs (loads have no LDS dep).
        if (kt + 32 < Ek) {
            const int kn = kt + 32;
            x0 = *(const float4*)(X + aIdx + kn);
            x1 = *(const float4*)(X + aIdx + kn + 4);
            x2 = *(const float4*)(X + aIdx + kn + 8);
            x3 = *(const float4*)(X + aIdx + kn + 12);
            wb = *(const uint4*)(Wh + bIdx + kn);
            wl = *(const uint4*)(Wl + bIdx + kn);
        }

        const short8 fa_h0 = *(const short8*)&Ah[wv*32 +      n16][quad*8];
        const short8 fa_l0 = *(const short8*)&Al[wv*32 +      n16][quad*8];
        const short8 fa_h1 = *(const short8*)&Ah[wv*32 + 16 + n16][quad*8];
        const short8 fa_l1 = *(const short8*)&Al[wv*32 + 16 + n16][quad*8];
#pragma unroll
        for (int ct = 0; ct < 4; ++ct) {
            const short8 fb_h = *(const short8*)&Bh[ct*16 + n16][quad*8];
            const short8 fb_l = *(const short8*)&Bl[ct*16 + n16][quad*8];
            acc[0][ct] = __builtin_amdgcn_mfma_f32_16x16x32_bf16(fa_h0, fb_h, acc[0][ct], 0, 0, 0);
            acc[0][ct] = __builtin_amdgcn_mfma_f32_16x16x32_bf16(fa_h0, fb_l, acc[0][ct], 0, 0, 0);
            acc[0][ct] = __builtin_amdgcn_mfma_f32_16x16x32_bf16(fa_l0, fb_h, acc[0][ct], 0, 0, 0);
            acc[1][ct] = __builtin_amdgcn_mfma_f32_16x16x32_bf16(fa_h1, fb_h, acc[1][ct], 0, 0, 0);
            acc[1][ct] = __builtin_amdgcn_mfma_f32_16x16x32_bf16(fa_h1, fb_l, acc[1][ct], 0, 0, 0);
            acc[1][ct] = __builtin_amdgcn_mfma_f32_16x16x32_bf16(fa_l1, fb_h, acc[1][ct], 0, 0, 0);
        }
    }

    // epilogue: D row = quad*4+reg (within 16-tile), col = n16
#pragma unroll
    for (int mt = 0; mt < 2; ++mt)
#pragma unroll
    for (int ct = 0; ct < 4; ++ct) {
        const int c  = nBase + ct*16 + n16;
        const float bv = bias[c];
#pragma unroll
        for (int reg = 0; reg < 4; ++reg) {
            const int m = mBase + wv*32 + mt*16 + quad*4 + reg;
            const float o = acc[mt][ct][reg] + bv;
            if (MODE == 0) {
                out[(size_t)m * Ek + c] = o;
            } else {
                const int bb2 = m >> 11, nn = m & 2047;
                const int hh2 = c >> 6,  dd = c & 63;
                const size_t sb = (size_t)(bb2*Hk + hh2) * Nk * DHk;
                out[sb + (size_t)nn * DHk + dd] = o;
                if (obf) {
                    const size_t kdst = sb + (size_t)(nn >> 4) * 1024
                                      + ((dd >> 5) * 512)
                                      + ((((dd >> 3) & 3) * 16 + (nn & 15)) * 8)
                                      + (dd & 7);
                    obf[kdst] = bf16rne(o);
                }
            }
        }
    }
}

// ---------------------------------------------------------------------------
__device__ __forceinline__ unsigned fkey(float s) {
    const unsigned b = __float_as_uint(s);
    return (b & 0x80000000u) ? ~b : (b | 0x80000000u);
}
__device__ __forceinline__ unsigned long long dkey(double s) {
    unsigned long long b = (unsigned long long)__double_as_longlong(s);
    return (b & 0x8000000000000000ull) ? ~b : (b | 0x8000000000000000ull);
}
__device__ __forceinline__ double dinv(unsigned long long u) {
    const unsigned long long b =
        (u & 0x8000000000000000ull) ? (u & 0x7fffffffffffffffull) : ~u;
    return __longlong_as_double((long long)b);
}

// ---------------------------------------------------------------------------
// DPP wave-64 reductions / scan (rocPRIM & LLVM AtomicOptimizer patterns).
// ---------------------------------------------------------------------------
__device__ __forceinline__ int dpp_wsum_i32(int x) {
#define STEP(C) x += __builtin_amdgcn_update_dpp(0, x, C, 0xf, 0xf, true);
    STEP(0x111) STEP(0x112) STEP(0x114) STEP(0x118) STEP(0x142) STEP(0x143)
#undef STEP
    return __builtin_amdgcn_readlane(x, 63);
}
__device__ __forceinline__ float dpp_wsum_f32(float x) {
#define STEP(C) { const int t_ = __builtin_amdgcn_update_dpp(0, __float_as_int(x), C, 0xf, 0xf, true); \
                  x += __int_as_float(t_); }
    STEP(0x111) STEP(0x112) STEP(0x114) STEP(0x118) STEP(0x142) STEP(0x143)
#undef STEP
    return __int_as_float(__builtin_amdgcn_readlane(__float_as_int(x), 63));
}
__device__ __forceinline__ float dpp_wmax_f32(float x) {
#define STEP(C) { const int t_ = __builtin_amdgcn_update_dpp(__float_as_int(x), __float_as_int(x), C, 0xf, 0xf, false); \
                  x = fmaxf(x, __int_as_float(t_)); }
    STEP(0x111) STEP(0x112) STEP(0x114) STEP(0x118) STEP(0x142) STEP(0x143)
#undef STEP
    return __int_as_float(__builtin_amdgcn_readlane(__float_as_int(x), 63));
}
__device__ __forceinline__ unsigned dpp_wmin_u32(unsigned x) {
#define STEP(C) { const unsigned t_ = (unsigned)__builtin_amdgcn_update_dpp((int)x, (int)x, C, 0xf, 0xf, false); \
                  x = x < t_ ? x : t_; }
    STEP(0x111) STEP(0x112) STEP(0x114) STEP(0x118) STEP(0x142) STEP(0x143)
#undef STEP
    return (unsigned)__builtin_amdgcn_readlane((int)x, 63);
}
__device__ __forceinline__ unsigned dpp_wmax_u32(unsigned x) {
#define STEP(C) { const unsigned t_ = (unsigned)__builtin_amdgcn_update_dpp((int)x, (int)x, C, 0xf, 0xf, false); \
                  x = x > t_ ? x : t_; }
    STEP(0x111) STEP(0x112) STEP(0x114) STEP(0x118) STEP(0x142) STEP(0x143)
#undef STEP
    return (unsigned)__builtin_amdgcn_readlane((int)x, 63);
}
// inclusive prefix-sum across 64 lanes (LLVM buildScan pattern)
__device__ __forceinline__ int dpp_wprefix_incl_i32(int x) {
    x += __builtin_amdgcn_update_dpp(0, x, 0x111, 0xf, 0xf, true);  // row_shr:1
    x += __builtin_amdgcn_update_dpp(0, x, 0x112, 0xf, 0xf, true);  // row_shr:2
    x += __builtin_amdgcn_update_dpp(0, x, 0x114, 0xf, 0xf, true);  // row_shr:4
    x += __builtin_amdgcn_update_dpp(0, x, 0x118, 0xf, 0xf, true);  // row_shr:8
    x += __builtin_amdgcn_update_dpp(0, x, 0x142, 0xa, 0xf, true);  // bcast15 -> rows 1,3
    x += __builtin_amdgcn_update_dpp(0, x, 0x143, 0xc, 0xf, true);  // bcast31 -> rows 2,3
    return x;
}

// ---------------------------------------------------------------------------
// Per-row top-k: prefilter -> f64 recheck -> exact top-64 + rank-65 blend.
// (unchanged - proven 295 us)
// ---------------------------------------------------------------------------
__device__ __forceinline__ void proc_row(
    const int lane, const int lrow,
    unsigned s0, unsigned s1, unsigned s2, unsigned s3,
    unsigned s4, unsigned s5, unsigned s6, unsigned s7,
    unsigned s8, unsigned s9, unsigned s10, unsigned s11,
    unsigned s12, unsigned s13, unsigned s14, unsigned s15,
    const float* __restrict__ Kb, const float (*qsf)[68],
    unsigned long long (*ck)[CANDCAP], unsigned (*ci)[CANDCAP],
    unsigned long long (*wvi)[64], unsigned (*eq_idx)[64],
    int& i65_out, float& lam_out)
{
    const unsigned long long lmask = (1ull << lane) - 1ull;

    // shifted copies: q_w = lo-half in compare space (hi-half compares use s_w)
    const unsigned q0 = s0 << 16,  q1 = s1 << 16,  q2 = s2 << 16,  q3 = s3 << 16;
    const unsigned q4 = s4 << 16,  q5 = s5 << 16,  q6 = s6 << 16,  q7 = s7 << 16;
    const unsigned q8 = s8 << 16,  q9 = s9 << 16,  q10 = s10 << 16, q11 = s11 << 16;
    const unsigned q12 = s12 << 16, q13 = s13 << 16, q14 = s14 << 16, q15 = s15 << 16;

    // A) bracket: per-lane top-2 over the 32 junk-space values.
    unsigned m1 = 0u, m2 = 0u;
#define T2(V) { const unsigned t_ = (V) < m1 ? (V) : m1; \
                m1 = m1 > (V) ? m1 : (V);  m2 = m2 > t_ ? m2 : t_; }
    T2(s0)  T2(s1)  T2(s2)  T2(s3)  T2(s4)  T2(s5)  T2(s6)  T2(s7)
    T2(s8)  T2(s9)  T2(s10) T2(s11) T2(s12) T2(s13) T2(s14) T2(s15)
    T2(q0)  T2(q1)  T2(q2)  T2(q3)  T2(q4)  T2(q5)  T2(q6)  T2(q7)
    T2(q8)  T2(q9)  T2(q10) T2(q11) T2(q12) T2(q13) T2(q14) T2(q15)
#undef T2
    unsigned lo16 = dpp_wmin_u32(m2) >> 16;   // count(>=lo16) >= 2/lane -> >=128
    unsigned hi16 = dpp_wmax_u32(m1) >> 16;   // count(>=hi16+1) == 0

    // binary search: largest TH with count >= PRECAND; window-accept [96,128]
    while (lo16 < hi16) {
        const unsigned mid = lo16 + ((hi16 - lo16) >> 1) + 1u;
        const unsigned M = mid << 16;
        int c0 = 0, c1 = 0, c2 = 0, c3 = 0;    // 4 accums: break dep chain
        c0 += (s0  >= M); c0 += (q0  >= M); c0 += (s1  >= M); c0 += (q1  >= M);
        c0 += (s2  >= M); c0 += (q2  >= M); c0 += (s3  >= M); c0 += (q3  >= M);
        c1 += (s4  >= M); c1 += (q4  >= M); c1 += (s5  >= M); c1 += (q5  >= M);
        c1 += (s6  >= M); c1 += (q6  >= M); c1 += (s7  >= M); c1 += (q7  >= M);
        c2 += (s8  >= M); c2 += (q8  >= M); c2 += (s9  >= M); c2 += (q9  >= M);
        c2 += (s10 >= M); c2 += (q10 >= M); c2 += (s11 >= M); c2 += (q11 >= M);
        c3 += (s12 >= M); c3 += (q12 >= M); c3 += (s13 >= M); c3 += (q13 >= M);
        c3 += (s14 >= M); c3 += (q14 >= M); c3 += (s15 >= M); c3 += (q15 >= M);
        const int c = dpp_wsum_i32((c0 + c1) + (c2 + c3));
        if (c >= PRECAND) {
            lo16 = mid;
            if (c <= CANDCAP) break;       // window accept (superset-safe)
        } else hi16 = mid - 1u;
    }
    const unsigned THsh = lo16 << 16;

    // collect candidates, LANE-MAJOR: per-lane count -> DPP prefix -> scatter
    int cnt = 0;
#define CC(S, Q) { cnt += ((Q) >= THsh); cnt += ((S) >= THsh); }
    CC(s0, q0)    CC(s1, q1)    CC(s2, q2)    CC(s3, q3)
    CC(s4, q4)    CC(s5, q5)    CC(s6, q6)    CC(s7, q7)
    CC(s8, q8)    CC(s9, q9)    CC(s10, q10)  CC(s11, q11)
    CC(s12, q12)  CC(s13, q13)  CC(s14, q14)  CC(s15, q15)
#undef CC
    const int incl = dpp_wprefix_incl_i32(cnt);
    int pos = incl - cnt;                       // exclusive prefix
    int nc = __builtin_amdgcn_readlane(incl, 63);
    if (nc > CANDCAP) nc = CANDCAP;
#define CE(W, S, Q) { \
        if ((Q) >= THsh) { \
            if (pos < CANDCAP) \
                ci[lrow][pos] = (unsigned)((((W) >> 2) * 512) + (((W) & 3) * 128) + 2 * lane); \
            ++pos; } \
        if ((S) >= THsh) { \
            if (pos < CANDCAP) \
                ci[lrow][pos] = (unsigned)((((W) >> 2) * 512) + (((W) & 3) * 128) + 2 * lane + 1); \
            ++pos; } }
    CE(0, s0, q0)     CE(1, s1, q1)     CE(2, s2, q2)     CE(3, s3, q3)
    CE(4, s4, q4)     CE(5, s5, q5)     CE(6, s6, q6)     CE(7, s7, q7)
    CE(8, s8, q8)     CE(9, s9, q9)     CE(10, s10, q10)  CE(11, s11, q11)
    CE(12, s12, q12)  CE(13, s13, q13)  CE(14, s14, q14)  CE(15, s15, q15)
#undef CE

    // B) f64 rescore from f32 q,k: lane = (c8, d8); 8 cands per batch
    const int c8 = lane >> 3, d8 = lane & 7;
    const float* qrow = &qsf[lrow][d8 * 8];
    const double qd0 = (double)qrow[0], qd1 = (double)qrow[1];
    const double qd2 = (double)qrow[2], qd3 = (double)qrow[3];
    const double qd4 = (double)qrow[4], qd5 = (double)qrow[5];
    const double qd6 = (double)qrow[6], qd7 = (double)qrow[7];
    const int nb = (nc + 7) >> 3;
    for (int b = 0; b < nb; ++b) {
        const int s  = b * 8 + c8;
        const int s2 = s < nc ? s : nc - 1;
        const unsigned cidx = ci[lrow][s2];
        const unsigned kb32 = (cidx << 6) + (unsigned)(d8 * 8);
        const float2 kv0 = *(const float2*)(Kb + kb32);
        const float2 kv1 = *(const float2*)(Kb + kb32 + 2);
        const float2 kv2 = *(const float2*)(Kb + kb32 + 4);
        const float2 kv3 = *(const float2*)(Kb + kb32 + 6);
        double acc = 0.0;
        acc = fma(qd0, (double)kv0.x, acc);
        acc = fma(qd1, (double)kv0.y, acc);
        acc = fma(qd2, (double)kv1.x, acc);
        acc = fma(qd3, (double)kv1.y, acc);
        acc = fma(qd4, (double)kv2.x, acc);
        acc = fma(qd5, (double)kv2.y, acc);
        acc = fma(qd6, (double)kv3.x, acc);
        acc = fma(qd7, (double)kv3.y, acc);
        acc += __shfl_xor(acc, 1);
        acc += __shfl_xor(acc, 2);
        acc += __shfl_xor(acc, 4);
        if (d8 == 0 && s < nc) ck[lrow][s] = dkey(acc * 0.125);
    }

    // C) exact top-64 among candidates (64-bit keys, <=2 per lane)
    const unsigned long long k0 = (lane      < nc) ? ck[lrow][lane]      : 0ull;
    const unsigned long long k1 = (lane + 64 < nc) ? ck[lrow][lane + 64] : 0ull;
    const unsigned idx0 = ci[lrow][lane];
    const unsigned idx1 = ci[lrow][(lane + 64) & (CANDCAP - 1)];
    const unsigned kh0 = (unsigned)(k0 >> 32), kh1 = (unsigned)(k1 >> 32);
    const unsigned kl0 = (unsigned)k0,         kl1 = (unsigned)k1;

    // stage 1: H = hi32 of 64th-largest key
    unsigned H;
    {
        const unsigned i0 = (k0 != 0ull) ? kh0 : 0xFFFFFFFFu;
        const unsigned i1 = (k1 != 0ull) ? kh1 : 0xFFFFFFFFu;
        unsigned lo = dpp_wmin_u32(i0 < i1 ? i0 : i1);
        unsigned hi = dpp_wmax_u32(kh0 > kh1 ? kh0 : kh1);
        bool done = false;
        while (lo < hi) {
            const unsigned mid = lo + ((hi - lo) >> 1) + 1u;
            const int c = __popcll(__ballot(kh0 >= mid))
                        + __popcll(__ballot(kh1 >= mid));
            if (c == 64) {
                const unsigned v0 = (kh0 >= mid) ? kh0 : 0xFFFFFFFFu;
                const unsigned v1m = (kh1 >= mid) ? kh1 : 0xFFFFFFFFu;
                H = dpp_wmin_u32(v0 < v1m ? v0 : v1m);
                done = true; break;
            }
            if (c >= 64) lo = mid; else hi = mid - 1u;
        }
        if (!done) H = lo;
    }
    const int cGtHi = __popcll(__ballot(kh0 > H))
                    + __popcll(__ballot(kh1 > H));
    const int need1 = 64 - cGtHi;

    // stage 2: Tlo = lo32 of 64th key (need1-th largest lo32 among hi==H)
    const bool e0v = (kh0 == H) && (k0 != 0ull);
    const bool e1v = (kh1 == H) && (k1 != 0ull);
    const int cEq = __popcll(__ballot(e0v)) + __popcll(__ballot(e1v));
    unsigned Tlo;
    if (need1 == cEq) {                // all ties included -> min lo32
        const unsigned v0 = e0v ? kl0 : 0xFFFFFFFFu;
        const unsigned v1m = e1v ? kl1 : 0xFFFFFFFFu;
        Tlo = dpp_wmin_u32(v0 < v1m ? v0 : v1m);
    } else if (need1 == 1) {           // single needed -> max lo32
        const unsigned v0 = e0v ? kl0 : 0u;
        const unsigned v1m = e1v ? kl1 : 0u;
        Tlo = dpp_wmax_u32(v0 > v1m ? v0 : v1m);
    } else {
        unsigned lo = 0u, hi = 0xFFFFFFFFu;
        bool done = false;
        while (lo < hi) {
            const unsigned mid = lo + ((hi - lo) >> 1) + 1u;
            const int c = __popcll(__ballot(e0v && kl0 >= mid))
                        + __popcll(__ballot(e1v && kl1 >= mid));
            if (c == need1) {
                const unsigned v0 = (e0v && kl0 >= mid) ? kl0 : 0xFFFFFFFFu;
                const unsigned v1m = (e1v && kl1 >= mid) ? kl1 : 0xFFFFFFFFu;
                Tlo = dpp_wmin_u32(v0 < v1m ? v0 : v1m);
                done = true; break;
            }
            if (c >= need1) lo = mid; else hi = mid - 1u;
        }
        if (!done) Tlo = lo;
    }
    const unsigned long long T = ((unsigned long long)H << 32) | Tlo;

    int base = 0;                      // emit k > T as packed (f32 val, idx)
    {
        const bool g0 = k0 > T;
        unsigned long long m = __ballot(g0);
        if (g0) {
            const int pos2 = base + __popcll(m & lmask);
            wvi[lrow][pos2] = ((unsigned long long)__float_as_uint((float)dinv(k0)) << 32)
                            | (unsigned long long)idx0;
        }
        base += __popcll(m);
        const bool g1 = k1 > T;
        m = __ballot(g1);
        if (g1) {
            const int pos2 = base + __popcll(m & lmask);
            wvi[lrow][pos2] = ((unsigned long long)__float_as_uint((float)dinv(k1)) << 32)
                            | (unsigned long long)idx1;
        }
        base += __popcll(m);
    }

    int ne = 0;                        // ties k == T
    {
        const bool e0 = k0 == T;
        unsigned long long m = __ballot(e0);
        if (e0) {
            const int pos2 = ne + __popcll(m & lmask);
            if (pos2 < 64) eq_idx[lrow][pos2] = idx0;
        }
        ne += __popcll(m);
        const bool e1 = k1 == T;
        m = __ballot(e1);
        if (e1) {
            const int pos2 = ne + __popcll(m & lmask);
            if (pos2 < 64) eq_idx[lrow][pos2] = idx1;
        }
        ne += __popcll(m);
    }
    if (ne > 64) ne = 64;

    const int   need = 64 - base;
    const float tvf  = (float)dinv(T);
    if (lane < need) {                 // ties: ascending index (jax rule)
        unsigned my = 0u;
        for (int j = 0; j < ne; ++j) {
            const unsigned v = eq_idx[lrow][j];
            int rank = 0;
            for (int j2 = 0; j2 < ne; ++j2) rank += (eq_idx[lrow][j2] < v) ? 1 : 0;
            if (rank == lane) my = v;
        }
        wvi[lrow][base + lane] = ((unsigned long long)__float_as_uint(tvf) << 32)
                               | (unsigned long long)my;
    }

    // 65th element (max key < T) via 2-stage DPP max (register-only)
    const unsigned mh0 = (k0 < T) ? kh0 : 0u;
    const unsigned mh1 = (k1 < T) ? kh1 : 0u;     // invalid k=0 -> contributes 0
    const unsigned Hm = dpp_wmax_u32(mh0 > mh1 ? mh0 : mh1);
    const unsigned ml0 = (k0 < T && kh0 == Hm) ? kl0 : 0u;
    const unsigned ml1 = (k1 < T && kh1 == Hm) ? kl1 : 0u;
    const unsigned Lm = dpp_wmax_u32(ml0 > ml1 ? ml0 : ml1);
    const unsigned long long m2k = ((unsigned long long)Hm << 32) | Lm;

    int i65 = 0;
    {
        unsigned long long mm = __ballot(k0 == m2k && m2k != 0ull);
        if (mm) i65 = __shfl((int)idx0, (int)(__ffsll((long long)mm) - 1));
        else {
            mm = __ballot(k1 == m2k && m2k != 0ull);
            if (mm) i65 = __shfl((int)idx1, (int)(__ffsll((long long)mm) - 1));
        }
    }
    double fr = (dinv(T) - dinv(m2k)) * (1.0 / BLENDW);
    if (fr > 1.0) fr = 1.0;
    i65_out = i65;
    lam_out = (m2k == 0ull) ? 0.f : (float)(0.5 * (1.0 - fr));
}

// ---------------------------------------------------------------------------
// MFMA-prefiltered attn (unchanged - proven 295 us): bf16 MFMA scores ->
// prefilter -> f64 recheck -> exact top-64 + rank-65 blend -> softmax + V.
// 1024 thr = 16 waves, one q-row per wave; keys in named scalars (no scratch).
// ---------------------------------------------------------------------------
__global__ __launch_bounds__(1024, 8) void attn_topk_mfma(
    const float* __restrict__ qf, const float* __restrict__ kf,
    const unsigned short* __restrict__ kbf,
    const float* __restrict__ vh, float* __restrict__ outm)
{
    // sc (16x516 f32 = 33024 B) aliased with ck (16x128 u64) + ci (16x128 u32)
    __shared__ __align__(16) char uS[33024];
    float (*sc)[516] = (float(*)[516])uS;
    unsigned long long (*ck)[CANDCAP] = (unsigned long long(*)[CANDCAP])uS;
    unsigned (*ci)[CANDCAP] = (unsigned(*)[CANDCAP])(uS + 16384);

    __shared__ float          qsf[16][68];         // f32 q rows (exact)
    __shared__ unsigned short qbf[16][72];         // bf16 q rows
    __shared__ unsigned long long wvi[16][64];     // packed (val|w, idx)
    __shared__ unsigned eq_idx[16][64];

    const int tid  = threadIdx.x;
    const int lane = tid & 63;
    const int wv   = tid >> 6;             // 0..15; wave wv owns q-row wv

    // XCD-aware bijective swizzle (grid 4096 = 8 XCDs x 512, 4096%8==0):
    // all 128 q-tiles of a slot on one XCD -> K/V stay L2-resident.
    const int wid  = (blockIdx.x & 7) * 512 + (blockIdx.x >> 3);
    const int slot = wid >> 7;             // 0..31 head slot
    const int qt   = wid & 127;
    const int bb   = slot >> 4;
    const int hh   = slot & 15;

    const float*          Qb = qf  + (size_t)slot * Nk * DHk + (size_t)qt * 16 * DHk;
    const float*          Kb = kf  + (size_t)slot * Nk * DHk;
    const unsigned short* KB = kbf + (size_t)slot * Nk * DHk;
    const float*          Vb = vh  + (size_t)slot * Nk * DHk;

    {   // stage 16 q rows: f32 + bf16 copies (1024 thr: 1 elem each)
        const int r = tid >> 6, d = tid & 63;
        const float qv = Qb[r * DHk + d];
        qsf[r][d] = qv;
        qbf[r][d] = bf16rne(qv);
    }
    __syncthreads();

    // A-fragments: A[m=lane&15][k=quad*8+j]
    const int n16  = lane & 15;
    const int quad = lane >> 4;
    short8 afrag0, afrag1;
    afrag0 = *(const short8*)&qbf[n16][quad * 8];
    afrag1 = *(const short8*)&qbf[n16][32 + quad * 8];

    // Packed hi-16 prefilter keys: 16 NAMED u32 words. Word w holds logical
    // keys {2w (lo), 2w+1 (hi)}; col(2w)=(w>>2)*512+(w&3)*128+2*lane, +1 odd.
    unsigned p0, p1, p2, p3, p4, p5, p6, p7;
    unsigned p8, p9, p10, p11, p12, p13, p14, p15;
    const int rowD = quad * 4;

    // ---- phase 1: bf16 MFMA scores, 4 chunks x 512 cols (manual unroll) ----
    // 16 waves x 2 MFMA-tiles per chunk cover the 32 ctiles. kbf is in
    // fragment-contiguous layout: tile t -> 1KB lane-linear block per half.
#define QK_TILE(CH, T, ACC) { \
    const unsigned short* kp = KB + (((CH) * 32) + (wv * 2 + (T))) * 1024 + lane * 8; \
    const short8 b0_ = *(const short8*)(kp); \
    const short8 b1_ = *(const short8*)(kp + 512); \
    ACC = __builtin_amdgcn_mfma_f32_16x16x32_bf16(afrag0, b0_, ACC, 0, 0, 0); \
    ACC = __builtin_amdgcn_mfma_f32_16x16x32_bf16(afrag1, b1_, ACC, 0, 0, 0); \
}
#define SC_STORE(T, ACC) { \
    const int ccol = (wv * 2 + (T)) * 16 + n16; \
    sc[rowD + 0][ccol] = ACC[0]; sc[rowD + 1][ccol] = ACC[1]; \
    sc[rowD + 2][ccol] = ACC[2]; sc[rowD + 3][ccol] = ACC[3]; \
}
#define PACKW(J, DEST) { \
    const float2 pr_ = *(const float2*)&sc[wv][(J) * 128 + 2 * lane]; \
    DEST = (fkey(pr_.x) >> 16) | ((fkey(pr_.y) >> 16) << 16); \
}
#define DO_CHUNK(CH, D0, D1, D2, D3) { \
    f32x4 ac0 = {0.f,0.f,0.f,0.f}, ac1 = {0.f,0.f,0.f,0.f}; \
    QK_TILE(CH, 0, ac0) QK_TILE(CH, 1, ac1) \
    __syncthreads();                   /* prev chunk's sc reads done */ \
    SC_STORE(0, ac0) SC_STORE(1, ac1) \
    __syncthreads(); \
    PACKW(0, D0) PACKW(1, D1) PACKW(2, D2) PACKW(3, D3) \
}
    DO_CHUNK(0, p0,  p1,  p2,  p3)
    DO_CHUNK(1, p4,  p5,  p6,  p7)
    DO_CHUNK(2, p8,  p9,  p10, p11)
    DO_CHUNK(3, p12, p13, p14, p15)
#undef DO_CHUNK
#undef PACKW
#undef SC_STORE
#undef QK_TILE

    __syncthreads();                       // sc dead; ck/ci alias safe

    // ---- per-row: prefilter -> f64 recheck -> exact top-64 + 65th ----
    int i65_0; float lam_0;
    proc_row(lane, wv,
             p0, p1, p2, p3, p4, p5, p6, p7,
             p8, p9, p10, p11, p12, p13, p14, p15,
             Kb, qsf, ck, ci, wvi, eq_idx, i65_0, lam_0);

    // ---- f32 softmax + V gather + boundary blend (one row per wave) ----
    {
        const unsigned long long e = wvi[wv][lane];
        const float    sv = __uint_as_float((unsigned)(e >> 32));
        const unsigned vi = (unsigned)e;
        const float mx = dpp_wmax_f32(sv);
        const float p  = __expf(sv - mx);
        const float Z  = dpp_wsum_f32(p);
        const float w  = p / Z;
        // overwrite val slot with softmax weight (wave-local row, DS in-order)
        wvi[wv][lane] = ((unsigned long long)__float_as_uint(w) << 32)
                      | (unsigned long long)vi;

        float acc = 0.f;
#pragma unroll
        for (int j = 0; j < 64; ++j) {
            const unsigned long long ej = wvi[wv][j];   // broadcast, imm offset
            const float wj = __uint_as_float((unsigned)(ej >> 32));
            const unsigned ij = (unsigned)ej;
            acc = fmaf(wj, Vb[(ij << 6) + (unsigned)lane], acc);
        }
        {   // hedge: position 63 holds the rank-64 (threshold) element
            const unsigned long long e63 = wvi[wv][63];
            const float    wT  = __uint_as_float((unsigned)(e63 >> 32));
            const unsigned i64 = (unsigned)e63;
            acc += wT * lam_0 *
                   (Vb[((unsigned)i65_0 << 6) + (unsigned)lane]
                  - Vb[(i64 << 6) + (unsigned)lane]);
        }
        const int gq = qt * 16 + wv;
        outm[((size_t)bb * Nk + gq) * Ek + hh * DHk + lane] = acc;
    }
}

// ---------------------------------------------------------------------------
extern "C" void kernel_launch(void* const* d_in, const int* in_sizes, int n_in,
                              void* d_out, int out_size, void* d_ws, size_t ws_size,
                              hipStream_t stream)
{
    const float* query = (const float*)d_in[0];
    const float* key   = (const float*)d_in[1];
    const float* value = (const float*)d_in[2];
    const float* Wq    = (const float*)d_in[3];
    const float* bq    = (const float*)d_in[4];
    const float* Wk    = (const float*)d_in[5];
    const float* bk    = (const float*)d_in[6];
    const float* Wv    = (const float*)d_in[7];
    const float* bv    = (const float*)d_in[8];
    const float* Wo    = (const float*)d_in[9];
    const float* bo    = (const float*)d_in[10];
    float* out = (float*)d_out;
    (void)in_sizes; (void)n_in; (void)out_size; (void)ws_size;

    // 88 MB: qf|kf|v|attn f32 (16 MB ea) + kbf (8) + whb|wlb (8 ea, 4 W's)
    const size_t seg  = (size_t)(Bk * Hk) * Nk * DHk;   // 4M elems
    const size_t wseg = (size_t)Ek * Ek;                 // 1M elems
    float* qfp = (float*)d_ws;
    float* kfp = qfp + seg;
    float* vws = kfp + seg;
    float* aws = vws + seg;
    unsigned short* kbf = (unsigned short*)(aws + seg);
    unsigned short* whb = kbf + seg;                     // 4 x wseg
    unsigned short* wlb = whb + 4 * wseg;                // 4 x wseg

    const dim3 blk(256);

    // 1) all 4 weight matrices -> bf16 hi/lo (one launch, 2048 blocks)
    hipLaunchKernelGGL(cvt_w, dim3(4 * 512), blk, 0, stream,
                       Wq, Wk, Wv, Wo, whb, wlb);
    // 2) fused Q/K/V projections (inline X conversion; K writes kbf)
    hipLaunchKernelGGL((gemm_mfma<1>), dim3(3 * 512), blk, 0, stream,
                       query, key, value, whb, wlb, bq, bk, bv,
                       qfp, kfp, vws, kbf);
    // 3) attention
    hipLaunchKernelGGL(attn_topk_mfma, dim3(32 * 128), dim3(1024), 0, stream,
                       qfp, kfp, kbf, vws, aws);
    // 4) output projection (inline X conversion; W = slot 3)
    hipLaunchKernelGGL((gemm_mfma<0>), dim3(512), blk, 0, stream,
                       aws, (const float*)nullptr, (const float*)nullptr,
                       whb + 3 * wseg, wlb + 3 * wseg,
                       bo, (const float*)nullptr, (const float*)nullptr,
                       out, (float*)nullptr, (float*)nullptr,
                       (unsigned short*)nullptr);
}